// Round 9
// baseline (3294.247 us; speedup 1.0000x reference)
//
#include <hip/hip_runtime.h>
#include <hip/hip_bf16.h>
#include <cmath>

typedef __bf16 bf;
typedef _Float16 fp16;
typedef __bf16 bfrag __attribute__((ext_vector_type(8)));
typedef __bf16 bf4 __attribute__((ext_vector_type(4)));
typedef _Float16 h4 __attribute__((ext_vector_type(4)));
typedef float  f32x4 __attribute__((ext_vector_type(4)));

constexpr int BSZ = 32, SEQ = 512, NVAR = 862, NMARK = 4, NTOK = 866;
constexpr int DM = 512, DS = 16, DTR = 32, DFF = 512, NL = 4, PRED = 96;
constexpr int M = BSZ * NTOK;              // 27712 tokens
constexpr float EPS = 1e-5f;
constexpr int NCH = 32, CL = 28;           // chunked scan: 32*28 = 896 >= 866
static_assert(NCH * CL >= NTOK, "chunks must cover sequence");

// async global -> LDS, 16B per lane (wave-uniform LDS base + lane*16)
__device__ __forceinline__ void gload16(const void* g, void* l) {
    __builtin_amdgcn_global_load_lds((const __attribute__((address_space(1))) void*)g,
                                     (__attribute__((address_space(3))) void*)l, 16, 0, 0);
}

// ---------------------------------------------------------------- f32 -> bf16
__global__ void cvt_kernel(const float* __restrict__ src, bf* __restrict__ dst, int n4) {
    int i = blockIdx.x * 256 + threadIdx.x;
    if (i >= n4) return;
    f32x4 v = ((const f32x4*)src)[i];
    bf o[4];
    o[0] = (bf)v[0]; o[1] = (bf)v[1]; o[2] = (bf)v[2]; o[3] = (bf)v[3];
    *(uint2*)&dst[i * 4] = *(uint2*)o;
}

// ---------------- build combined dt/bc weight: [ld][544][512] bf16
// rows 0..511: Fold = Wdt(512x32)·Wx[0:32]  ;  rows 512..543: Wx[32:64] (B,C)
__global__ void fold_kernel(const float* __restrict__ Wdt, const float* __restrict__ Wx,
                            bf* __restrict__ out) {
    int idx = blockIdx.x * 256 + threadIdx.x;     // NL*2*544*512 total
    int k = idx & 511; int rest = idx >> 9;
    int row = rest % 544; int ld = rest / 544;
    float s;
    if (row < 512) {
        const float* wd = Wdt + ((size_t)ld * 512 + row) * 32;
        const float* wx = Wx + (size_t)ld * 64 * 512 + k;
        s = 0.f;
#pragma unroll 8
        for (int r = 0; r < 32; r++) s += wd[r] * wx[(size_t)r * 512];
    } else {
        s = Wx[(size_t)ld * 64 * 512 + (size_t)(32 + row - 512) * 512 + k];
    }
    out[((size_t)ld * 544 + row) * 512 + k] = (bf)s;
}

// ---------------------------------------------------------------- mean / std
__global__ __launch_bounds__(256) void meanstd_kernel(const float* __restrict__ xe,
                               float* __restrict__ mean, float* __restrict__ stdv) {
    __shared__ float sm[2][4][64];
    int b = blockIdx.y;
    int vl = threadIdx.x & 63;
    int tg = threadIdx.x >> 6;
    int v = blockIdx.x * 64 + vl;
    float s = 0.f, sq = 0.f;
    if (v < NVAR) {
        const float* p = xe + (size_t)b * SEQ * NVAR + (size_t)tg * 128 * NVAR + v;
#pragma unroll 4
        for (int t = 0; t < 128; t++) {
            float x = p[(size_t)t * NVAR];
            s += x; sq += x * x;
        }
    }
    sm[0][tg][vl] = s; sm[1][tg][vl] = sq;
    __syncthreads();
    if (tg == 0 && v < NVAR) {
        s  = sm[0][0][vl] + sm[0][1][vl] + sm[0][2][vl] + sm[0][3][vl];
        sq = sm[1][0][vl] + sm[1][1][vl] + sm[1][2][vl] + sm[1][3][vl];
        float mu = s * (1.f / SEQ);
        float var = sq * (1.f / SEQ) - mu * mu;
        mean[b * NVAR + v] = mu;
        stdv[b * NVAR + v] = sqrtf(var + EPS);
    }
}

// ------------------------------------------------- tok build (transpose+norm)
__global__ void tok_kernel(const float* __restrict__ xe, const float* __restrict__ xm,
                           const float* __restrict__ mean, const float* __restrict__ stdv,
                           bf* __restrict__ tok) {
    __shared__ float tile[32][33];
    int b = blockIdx.z;
    int v0 = blockIdx.x * 32, s0 = blockIdx.y * 32;
    int tx = threadIdx.x, ty = threadIdx.y;  // 32 x 8
    int v = v0 + tx;
    float mu = 0.f, rs = 0.f;
    if (v < NVAR) { mu = mean[b * NVAR + v]; rs = 1.f / stdv[b * NVAR + v]; }
#pragma unroll
    for (int j = 0; j < 4; j++) {
        int s = s0 + ty + j * 8;
        float val = 0.f;
        if (v < NVAR)       val = (xe[((size_t)b * SEQ + s) * NVAR + v] - mu) * rs;
        else if (v < NTOK)  val = xm[((size_t)b * SEQ + s) * NMARK + (v - NVAR)];
        tile[ty + j * 8][tx] = val;
    }
    __syncthreads();
#pragma unroll
    for (int j = 0; j < 4; j++) {
        int n = v0 + ty + j * 8;
        if (n < NTOK)
            tok[((size_t)b * NTOK + n) * SEQ + s0 + tx] = (bf)tile[tx][ty + j * 8];
    }
}

// ---------------------------------------------------------------- GEMM
// C[M,N] = A[M,K](bf16) * W[N,K]^T (bf16), f32 accumulate.
// 64x128 tile, 8 waves / 512 threads; each wave owns 32x32 output (acc = 16
// VGPR). LDS = 48 KB double-buffered -> 3 blocks/CU (R8 post-mortem: the
// 64 KB 128x128 config was capped at ~1.6 blocks/CU, occupancy 26%).
// Counted-vmcnt pipeline: stage tile t+1 (3 loads/thread), s_waitcnt
// vmcnt(3) (waits only tile t's loads), raw s_barrier, compute.
// DTBC: dt output stored as fp16 (CT=_Float16), B/C as f32 to C2.
template <int BN, int ACT, bool BIAS, bool RES, bool HEAD, bool DTBC, typename CT>
__global__ __launch_bounds__(512, 6) void gemm_kernel(
    const bf* __restrict__ A0, const bf* __restrict__ A1,
    const bf* __restrict__ W0, const bf* __restrict__ W1,
    CT* __restrict__ C, float* __restrict__ C2,
    const float* __restrict__ bias, const bf* __restrict__ res,
    int Mreal, int Nreal, int K, int lda, int ldw, int ksplit, int ldc,
    size_t sAz, size_t sWz, size_t sCz, size_t sC2z, size_t sBiasz,
    const float* __restrict__ mean, const float* __restrict__ stdv) {
    constexpr int BM = 64, BK = 64;
    static_assert(BN == 128, "8-wave layout assumes 64x128 tile");
    __shared__ __align__(16) bf Als[2][BM * BK];
    __shared__ __align__(16) bf Bls[2][BN * BK];

    // ---- XCD-chunked bijective remap (m204 formula), n fastest within m ----
    int gx = gridDim.x, gy = gridDim.y;
    int gxy = gx * gy;
    int nbt = gxy * gridDim.z;
    int id = blockIdx.x + gx * (blockIdx.y + gy * blockIdx.z);
    int q8 = nbt >> 3, r8 = nbt & 7;
    int xcd = id & 7, rank = id >> 3;
    int w = xcd * q8 + (xcd < r8 ? xcd : r8) + rank;
    int z = w / gxy;
    int rem = w - z * gxy;
    int m0 = (rem / gy) * BM;
    int n0 = (rem % gy) * BN;

    A0 += (size_t)z * sAz; W0 += (size_t)z * sWz; C += (size_t)z * sCz;
    if (DTBC) C2 += (size_t)z * sC2z;
    if (BIAS) bias += (size_t)z * sBiasz;
    int tid = threadIdx.x, lane = tid & 63, wave = tid >> 6;   // 0..7
    int wm = wave >> 2, wn = wave & 3;        // 2 row-halves x 4 col-quarters
    int q = lane >> 4, ml = lane & 15;
    // staging: lane -> row (lane>>3) within 8-row group; swizzled source chunk
    int srow = lane >> 3;
    int aswz = ((lane & 7) ^ srow) * 8;          // global col offset (elems)
    // fragment read swizzle (chunk ^ row&7), kk folds in via XOR
    int swz = ((q ^ (ml & 7))) * 8;

    f32x4 acc[2][2];
#pragma unroll
    for (int i = 0; i < 2; i++)
#pragma unroll
        for (int j = 0; j < 2; j++) { acc[i][j][0] = 0.f; acc[i][j][1] = 0.f; acc[i][j][2] = 0.f; acc[i][j][3] = 0.f; }

    // per-wave: 3 async loads per stage (1 A row-group + 2 B row-groups)
    auto stage = [&](int kt, int buf) {
        const bf* ab = (ksplit && kt >= ksplit) ? (A1 + (kt - ksplit)) : (A0 + kt);
        const bf* wb = (ksplit && kt >= ksplit) ? (W1 + (kt - ksplit)) : (W0 + kt);
        {
            int r = wave * 8;                  // 8 waves x 8 rows = 64 A rows
            gload16(ab + (size_t)(m0 + r + srow) * lda + aswz, &Als[buf][r * BK]);
        }
#pragma unroll
        for (int i = 0; i < 2; i++) {
            int r = wave * 16 + i * 8;         // 8 waves x 16 rows = 128 B rows
            gload16(wb + (size_t)(n0 + r + srow) * ldw + aswz, &Bls[buf][r * BK]);
        }
    };

    stage(0, 0);
    int cur = 0;
    for (int kt = 0; kt < K; kt += BK) {
        bool pf = (kt + BK < K);
        if (pf) stage(kt + BK, cur ^ 1);       // prefetch next tile (3 loads)
        // wait for THIS tile's 3 loads only (next tile's 3 stay in flight)
        if (pf) asm volatile("s_waitcnt vmcnt(3)" ::: "memory");
        else    asm volatile("s_waitcnt vmcnt(0)" ::: "memory");
        __builtin_amdgcn_s_barrier();           // all waves' tile-t data in LDS
        __builtin_amdgcn_sched_barrier(0);      // pin LDS reads after barrier
#pragma unroll
        for (int kk = 0; kk < BK; kk += 32) {
            bfrag af[2], bff[2];
#pragma unroll
            for (int i = 0; i < 2; i++)
                af[i] = *(bfrag*)&Als[cur][(wm * 32 + i * 16 + ml) * BK + (swz ^ kk)];
#pragma unroll
            for (int j = 0; j < 2; j++)
                bff[j] = *(bfrag*)&Bls[cur][(wn * 32 + j * 16 + ml) * BK + (swz ^ kk)];
#pragma unroll
            for (int i = 0; i < 2; i++)
#pragma unroll
                for (int j = 0; j < 2; j++)
                    acc[i][j] = __builtin_amdgcn_mfma_f32_16x16x32_bf16(bff[j], af[i], acc[i][j], 0, 0, 0);
        }
        __builtin_amdgcn_sched_barrier(0);      // pin LDS reads before barrier
        __builtin_amdgcn_s_barrier();           // all waves done reading cur
        cur ^= 1;
    }

    // epilogue: acc[i][j][r] -> row = m0+wm*32+i*16+ml ; col = n0+wn*32+j*16+q*4+r
#pragma unroll
    for (int i = 0; i < 2; i++) {
        int row = m0 + wm * 32 + i * 16 + ml;
        if (row >= Mreal) continue;
#pragma unroll
        for (int j = 0; j < 2; j++) {
            int colb = n0 + wn * 32 + j * 16 + q * 4;
            if (colb >= Nreal) continue;          // N multiples of 4 -> whole quad in/out
            f32x4 x = acc[i][j];
            if constexpr (BIAS) {
                if (!DTBC || colb < 512) {
                    f32x4 bv = *(const f32x4*)&bias[colb];
#pragma unroll
                    for (int r = 0; r < 4; r++) x[r] += bv[r];
                }
            }
            if constexpr (DTBC) {
                if (colb < 512) {
                    h4 hv;
#pragma unroll
                    for (int r = 0; r < 4; r++) {
                        float xs = (x[r] > 20.f) ? x[r] : __logf(1.f + __expf(x[r]));  // softplus
                        hv[r] = (_Float16)xs;
                    }
                    *(h4*)&C[(size_t)row * 512 + colb] = hv;        // CT=_Float16
                } else {
                    *(f32x4*)&C2[(size_t)row * 32 + (colb - 512)] = x;
                }
            } else {
                if constexpr (ACT == 1) {
#pragma unroll
                    for (int r = 0; r < 4; r++)
                        x[r] = 0.5f * x[r] * (1.f + erff(x[r] * 0.70710678118654752f));
                }
                if constexpr (RES) {
                    bf4 rv = *(const bf4*)&res[(size_t)row * DM + colb];
#pragma unroll
                    for (int r = 0; r < 4; r++) x[r] += (float)rv[r];
                }
                if constexpr (HEAD) {
                    int bidx = row / NTOK, n = row - bidx * NTOK;
                    if (n < NVAR) {
                        float sc = stdv[bidx * NVAR + n], mm = mean[bidx * NVAR + n];
#pragma unroll
                        for (int r = 0; r < 4; r++) {
                            int col = colb + r;
                            if (col < Nreal)
                                C[((size_t)bidx * PRED + col) * NVAR + n] = (CT)(x[r] * sc + mm);
                        }
                    }
                } else {
                    bf4 ov;
#pragma unroll
                    for (int r = 0; r < 4; r++) ov[r] = (bf)x[r];
                    *(bf4*)&C[(size_t)row * ldc + colb] = ov;
                }
            }
        }
    }
    if (HEAD && blockIdx.x == 0 && blockIdx.y == 0 && blockIdx.z == 0 && tid == 0)
        C[(size_t)BSZ * PRED * NVAR] = (CT)0.f;  // loss_reg = 0
}

// ---------------------------------------------------------------- conv + silu
__global__ void conv_kernel(const bf* __restrict__ xz, const float* __restrict__ cw,
                            const float* __restrict__ cb, bf* __restrict__ xc, int Mc) {
    int id = blockIdx.x * 256 + threadIdx.x;   // 2*Mc*64 total
    int dir = id / (Mc * 64); int rem = id - dir * (Mc * 64);
    int token = rem >> 6; int ch0 = (rem & 63) * 8;
    int t = token % NTOK;
    const bf* xb = xz + (size_t)token * (4 * DM) + dir * (2 * DM) + ch0;
    bfrag xt = *(const bfrag*)xb;
    bfrag xn;
#pragma unroll
    for (int i = 0; i < 8; i++) xn[i] = (bf)0.f;
    int tn = dir ? t + 1 : t - 1;
    if ((unsigned)tn < (unsigned)NTOK)
        xn = *(const bfrag*)(xb + (dir ? (4 * DM) : -(4 * DM)));
    const float2* cwp = (const float2*)cw + ((size_t)dir * DM + ch0);
    const float*  cbp = cb + (size_t)dir * DM + ch0;
    bfrag ov;
#pragma unroll
    for (int jj = 0; jj < 8; jj++) {
        float2 w = cwp[jj];
        float x = (float)xn[jj] * w.x + (float)xt[jj] * w.y + cbp[jj];
        x = x / (1.f + __expf(-x));
        ov[jj] = (bf)x;
    }
    *(bfrag*)(xc + (size_t)dir * Mc * DM + (size_t)token * DM + ch0) = ov;
}

// ---------------------------------------------------------------- chunked scan
// Each lane owns 4 consecutive channels (8B vector global ops, LDS row
// broadcast amortized 4x, 4-way ILP in the h-recurrence). 128-thread blocks
// (2 waves: cg = wid). NCH=32: the packed kernel is issue-bound, so halving
// chunk count keeps time ~flat while halving hloc/dtsums state traffic.
// hloc layout channel-major: [g][c][s][d] (16 x 512 f32 per chunk).
template <bool FINAL>
__global__ __launch_bounds__(128, 2) void scan_chunk_kernel(
    const fp16* __restrict__ dtc, const float* __restrict__ dbc,
    const bf* __restrict__ xc, const bf* __restrict__ xz,
    const float* __restrict__ Alog, const float* __restrict__ Dp,
    float* __restrict__ hloc, float* __restrict__ dtsums,
    bf* __restrict__ y, int Mc) {
    __shared__ __align__(16) float row[2][32];
    int wid = threadIdx.x >> 6;                // cg: channel group 0/1
    int lane = threadIdx.x & 63;
    int b = blockIdx.x;
    int zc = blockIdx.y; int dir = zc / NCH, c = zc - dir * NCH;
    int d0 = wid * 256 + lane * 4;             // 4 consecutive channels
    int dd0 = dir * DM + d0;

    constexpr float L2E = 1.4426950408889634f;
    float A20[4];
    bool lc = true;
#pragma unroll
    for (int cc = 0; cc < 4; cc++) {
        const f32x4* ap = (const f32x4*)(Alog + (size_t)(dd0 + cc) * DS);
        float a2[16];
#pragma unroll
        for (int i = 0; i < 4; i++) {
            f32x4 v = ap[i];
#pragma unroll
            for (int jj = 0; jj < 4; jj++)
                a2[i * 4 + jj] = -__expf(v[jj]) * L2E;
        }
        A20[cc] = a2[0];
#pragma unroll
        for (int s = 1; s < 16; s++)
            lc = lc && (fabsf(a2[s] - (s + 1) * a2[0]) <= 1e-4f * fabsf(a2[s]));
    }
    bool fast = (__ballot(lc) == ~0ull);
    float Dd[4];
#pragma unroll
    for (int cc = 0; cc < 4; cc++) Dd[cc] = FINAL ? Dp[dd0 + cc] : 0.f;

    const size_t hbase = ((size_t)(b * 2 + dir) * NCH + c) * 8192;   // 16*512
    float h[4][16];
    if (FINAL) {
#pragma unroll
        for (int s = 0; s < 16; s++) {
            f32x4 hv = *(const f32x4*)&hloc[hbase + (size_t)s * 512 + d0];
#pragma unroll
            for (int cc = 0; cc < 4; cc++) h[cc][s] = hv[cc];
        }
    } else {
#pragma unroll
        for (int cc = 0; cc < 4; cc++)
#pragma unroll
            for (int s = 0; s < 16; s++) h[cc][s] = 0.f;
    }
    float dtsum[4] = {0.f, 0.f, 0.f, 0.f};

    const int t0 = c * CL;
    const int t1e = (t0 + CL < NTOK) ? t0 + CL : NTOK;
    const long step = dir ? -1 : 1;

    const fp16* dtp = nullptr; const float* bcp = nullptr;
    const bf* xcp = nullptr; const bf* xzp = nullptr; bf* yp = nullptr;
    h4 dtq = {(_Float16)0.f, (_Float16)0.f, (_Float16)0.f, (_Float16)0.f};
    bf4 xq; bf4 zq;
#pragma unroll
    for (int cc = 0; cc < 4; cc++) { xq[cc] = (bf)0.f; zq[cc] = (bf)0.f; }
    f32x4 gq = {0.f, 0.f, 0.f, 0.f};
    if (t0 < t1e) {
        long tok0 = (long)b * NTOK + (dir ? (NTOK - 1 - t0) : t0);
        dtp = dtc + (size_t)dir * Mc * 512 + (size_t)tok0 * 512 + d0;
        bcp = dbc + ((size_t)dir * Mc + (size_t)tok0) * 32;
        xcp = xc + (size_t)dir * Mc * 512 + (size_t)tok0 * 512 + d0;
        dtq = *(const h4*)dtp;
        if (lane < 8) gq = ((const f32x4*)bcp)[lane];
        xq = *(const bf4*)xcp;
        if (FINAL) {
            xzp = xz + (size_t)tok0 * 2048 + dir * 1024 + 512 + d0;
            yp  = y  + (size_t)tok0 * 1024 + dir * 512 + d0;
            zq = *(const bf4*)xzp;
        }
    }
    const long sdt = step * 512, sbc = step * 32, sxc = step * 512;
    const long sxz = step * 2048, sy = step * 1024;

    for (int t = t0; t < t1e; t++) {
        if (lane < 8) ((f32x4*)row[wid])[lane] = gq;
        float dtv[4], xv[4], zv[4], dtx[4];
#pragma unroll
        for (int cc = 0; cc < 4; cc++) {
            dtv[cc] = (float)dtq[cc];
            xv[cc] = (float)xq[cc];
            if (FINAL) zv[cc] = (float)zq[cc];
            dtx[cc] = dtv[cc] * xv[cc];
            dtsum[cc] += dtv[cc];
        }
        bf* ypc = yp;
        if (t + 1 < t1e) {                     // prefetch next token
            dtp += sdt; bcp += sbc; xcp += sxc;
            dtq = *(const h4*)dtp;
            if (lane < 8) gq = ((const f32x4*)bcp)[lane];
            xq = *(const bf4*)xcp;
            if (FINAL) { xzp += sxz; zq = *(const bf4*)xzp; yp += sy; }
        }
        const f32x4* rv = (const f32x4*)row[wid];
        float yva[4] = {0.f, 0.f, 0.f, 0.f};
        if (fast) {
            float r[4], r2[4], r3[4], r4[4], bse[4];
#pragma unroll
            for (int cc = 0; cc < 4; cc++) {
                r[cc] = exp2f(dtv[cc] * A20[cc]);
                r2[cc] = r[cc] * r[cc]; r3[cc] = r2[cc] * r[cc]; r4[cc] = r2[cc] * r2[cc];
                bse[cc] = r[cc];
            }
#pragma unroll
            for (int i = 0; i < 4; i++) {
                f32x4 Bv = rv[i];
                f32x4 Cv = rv[4 + i];
#pragma unroll
                for (int cc = 0; cc < 4; cc++) {
                    int s = i * 4;
                    float p0 = bse[cc], p1 = p0 * r[cc], p2 = p0 * r2[cc], p3 = p0 * r3[cc];
                    h[cc][s + 0] = p0 * h[cc][s + 0] + dtx[cc] * Bv[0];
                    h[cc][s + 1] = p1 * h[cc][s + 1] + dtx[cc] * Bv[1];
                    h[cc][s + 2] = p2 * h[cc][s + 2] + dtx[cc] * Bv[2];
                    h[cc][s + 3] = p3 * h[cc][s + 3] + dtx[cc] * Bv[3];
                    if (FINAL)
                        yva[cc] += Cv[0] * h[cc][s + 0] + Cv[1] * h[cc][s + 1]
                                 + Cv[2] * h[cc][s + 2] + Cv[3] * h[cc][s + 3];
                    bse[cc] *= r4[cc];
                }
            }
        } else {
            // slow path (never taken for this model's Alog; kept for correctness)
#pragma unroll
            for (int i = 0; i < 4; i++) {
                f32x4 Bv = rv[i];
                f32x4 Cv = rv[4 + i];
#pragma unroll
                for (int cc = 0; cc < 4; cc++) {
#pragma unroll
                    for (int jj = 0; jj < 4; jj++) {
                        int s = i * 4 + jj;
                        float A2 = -__expf(Alog[(size_t)(dd0 + cc) * DS + s]) * L2E;
                        float a = exp2f(dtv[cc] * A2);
                        h[cc][s] = a * h[cc][s] + dtx[cc] * Bv[jj];
                        if (FINAL) yva[cc] += Cv[jj] * h[cc][s];
                    }
                }
            }
        }
        if (FINAL) {
            bf4 ov;
#pragma unroll
            for (int cc = 0; cc < 4; cc++) {
                float sz = zv[cc] / (1.f + __expf(-zv[cc]));
                ov[cc] = (bf)((yva[cc] + Dd[cc] * xv[cc]) * sz);
            }
            *(bf4*)ypc = ov;
        }
    }
    if (!FINAL) {
#pragma unroll
        for (int s = 0; s < 16; s++) {
            f32x4 hv;
#pragma unroll
            for (int cc = 0; cc < 4; cc++) hv[cc] = h[cc][s];
            *(f32x4*)&hloc[hbase + (size_t)s * 512 + d0] = hv;
        }
        f32x4 dv;
#pragma unroll
        for (int cc = 0; cc < 4; cc++) dv[cc] = dtsum[cc];
        *(f32x4*)&dtsums[((size_t)(b * 2 + dir) * NCH + c) * 512 + d0] = dv;
    }
}

// Phase B: combine chunk summaries (serial over NCH chunks per group).
// hloc layout [g][c][s][d]; dtsums [g][c][d]. One thread per (g,s,d):
// coalesced on d. aprod = exp2(dtsum * A2[s]) computed on the fly.
__global__ void scan_fix_kernel(float* __restrict__ hloc, const float* __restrict__ dtsums,
                                const float* __restrict__ Alog, int total) {
    int tid = blockIdx.x * 256 + threadIdx.x;
    if (tid >= total) return;
    int d = tid & 511;
    int s = (tid >> 9) & 15;
    int g = tid >> 13;                 // b*2+dir
    int dir = g & 1;
    float A2s = -__expf(Alog[((size_t)(dir * DM + d)) * DS + s]) * 1.4426950408889634f;
    size_t i0 = (size_t)g * NCH * 8192 + (size_t)s * 512 + d;
    size_t d0 = (size_t)g * NCH * 512 + d;
    float H = 0.f;
#pragma unroll 8
    for (int c = 0; c < NCH; c++) {
        size_t ix = i0 + (size_t)c * 8192;
        float hl = hloc[ix];
        float ap = exp2f(dtsums[d0 + (size_t)c * 512] * A2s);
        hloc[ix] = H;
        H = hl + ap * H;
    }
}

// ---------------------------------------------------------------- LayerNorm
__global__ __launch_bounds__(256) void ln_kernel(const bf* X, bf* Y,
                                                 const float* __restrict__ g, const float* __restrict__ bb) {
    int token = blockIdx.x * 4 + (threadIdx.x >> 6);
    int lane = threadIdx.x & 63;
    bfrag xv = *(const bfrag*)(X + (size_t)token * DM + lane * 8);
    float xf[8]; float s = 0.f, sq = 0.f;
#pragma unroll
    for (int j = 0; j < 8; j++) { xf[j] = (float)xv[j]; s += xf[j]; sq += xf[j] * xf[j]; }
#pragma unroll
    for (int o = 1; o < 64; o <<= 1) { s += __shfl_xor(s, o); sq += __shfl_xor(sq, o); }
    float mu = s * (1.f / DM);
    float rs = rsqrtf(sq * (1.f / DM) - mu * mu + EPS);
    f32x4 g0 = ((const f32x4*)g)[lane * 2], g1 = ((const f32x4*)g)[lane * 2 + 1];
    f32x4 b0 = ((const f32x4*)bb)[lane * 2], b1 = ((const f32x4*)bb)[lane * 2 + 1];
    bfrag ov;
#pragma unroll
    for (int j = 0; j < 8; j++) {
        float gg = (j < 4) ? g0[j] : g1[j - 4];
        float bbv = (j < 4) ? b0[j] : b1[j - 4];
        ov[j] = (bf)((xf[j] - mu) * rs * gg + bbv);
    }
    *(bfrag*)(Y + (size_t)token * DM + lane * 8) = ov;
}

// ---------------------------------------------------------------- launch
extern "C" void kernel_launch(void* const* d_in, const int* in_sizes, int n_in,
                              void* d_out, int out_size, void* d_ws, size_t ws_size,
                              hipStream_t stream) {
    const float* x_enc = (const float*)d_in[0];
    const float* x_mark = (const float*)d_in[1];
    const float* W_emb = (const float*)d_in[4];
    const float* b_emb = (const float*)d_in[5];
    const float* mWin = (const float*)d_in[6];
    const float* mcw = (const float*)d_in[7];
    const float* mcb = (const float*)d_in[8];
    const float* mWx = (const float*)d_in[9];
    const float* mWdt = (const float*)d_in[10];
    const float* mbdt = (const float*)d_in[11];
    const float* mAlog = (const float*)d_in[12];
    const float* mD = (const float*)d_in[13];
    const float* mWout = (const float*)d_in[14];
    const float* W1w = (const float*)d_in[15];
    const float* b1w = (const float*)d_in[16];
    const float* W2w = (const float*)d_in[17];
    const float* b2w = (const float*)d_in[18];
    const float* ln1g = (const float*)d_in[19];
    const float* ln1b = (const float*)d_in[20];
    const float* ln2g = (const float*)d_in[21];
    const float* ln2b = (const float*)d_in[22];
    const float* lnfg = (const float*)d_in[23];
    const float* lnfb = (const float*)d_in[24];
    const float* headW = (const float*)d_in[25];
    const float* headb = (const float*)d_in[26];

    auto a256 = [](size_t x) { return (x + 255) & ~(size_t)255; };
    char* ws = (char*)d_ws;
    size_t off = 0;
    auto alloc = [&](size_t n) { size_t r = off; off += a256(n); return ws + r; };
    float* mean = (float*)alloc((size_t)BSZ * NVAR * 4);
    float* stdv = (float*)alloc((size_t)BSZ * NVAR * 4);
    bf* h  = (bf*)alloc((size_t)M * DM * 2);
    bf* t1 = (bf*)alloc((size_t)M * DM * 2);   // tok / hsum / ff
    bf* t2 = (bf*)alloc((size_t)M * DM * 2);   // h2
    // bf16-converted GEMM weights
    constexpr int nEmb = 512 * 512, nWin = NL * 2 * 1024 * 512,
                  nWout = NL * 2 * 512 * 512, nW1 = NL * DFF * DM, nW2 = NL * DM * DFF,
                  nHead = PRED * DM, nComb = NL * 2 * 544 * 512;
    bf* wEmb  = (bf*)alloc((size_t)nEmb * 2);
    bf* wWin  = (bf*)alloc((size_t)nWin * 2);
    bf* wWout = (bf*)alloc((size_t)nWout * 2);
    bf* wW1   = (bf*)alloc((size_t)nW1 * 2);
    bf* wW2   = (bf*)alloc((size_t)nW2 * 2);
    bf* wHead = (bf*)alloc((size_t)nHead * 2);
    bf* wComb = (bf*)alloc((size_t)nComb * 2);
    size_t fixedEnd = off;

    // adaptive chunk size: CB batches per chunk
    auto scanScr = [&](size_t cb) { return cb * 2 * (size_t)NCH * 8192 * 4; };  // hloc
    auto dtsScr  = [&](size_t cb) { return cb * 2 * (size_t)NCH * 512 * 4; };   // dtsums
    int CB = 1;
    {
        int cbs[6] = {32, 16, 8, 4, 2, 1};
        for (int i = 0; i < 6; i++) {
            size_t mc = (size_t)cbs[i] * NTOK;
            size_t chunkB = a256(mc * 4096) + a256(mc * 2048) + a256(mc * 256)
                          + a256(mc * 2048) + a256(mc * 2048)
                          + a256(scanScr(cbs[i])) + a256(dtsScr(cbs[i]));
            if (fixedEnd + chunkB <= ws_size) { CB = cbs[i]; break; }
        }
    }
    const size_t Mc = (size_t)CB * NTOK;
    size_t co = fixedEnd;
    bf* xzc = (bf*)(ws + co);        co += a256(Mc * 4096);
    bf* xcc = (bf*)(ws + co);        co += a256(Mc * 2048);
    float* dbcc = (float*)(ws + co); co += a256(Mc * 256);
    bf* ycc = (bf*)(ws + co);        co += a256(Mc * 2048);
    fp16* dtcc = (fp16*)(ws + co);   co += a256(Mc * 2048);   // fp16, 2 dirs x 512
    float* hloc = (float*)(ws + co); co += a256(scanScr(CB));
    float* dtsums = (float*)(ws + co);
    const int NC = BSZ / CB;
    const int MTc = (int)((Mc + 63) / 64);     // BM=64 m-panels
    constexpr int MT = (M + 63) / 64;          // 433 (exact: 27712 = 433*64)
    const int fixTotal = CB * 2 * 16 * 512;

    // weight conversion f32 -> bf16, and combined dt/bc weight build
    cvt_kernel<<<(nEmb / 4 + 255) / 256, 256, 0, stream>>>(W_emb, wEmb, nEmb / 4);
    cvt_kernel<<<(nWin / 4 + 255) / 256, 256, 0, stream>>>(mWin, wWin, nWin / 4);
    cvt_kernel<<<(nWout / 4 + 255) / 256, 256, 0, stream>>>(mWout, wWout, nWout / 4);
    cvt_kernel<<<(nW1 / 4 + 255) / 256, 256, 0, stream>>>(W1w, wW1, nW1 / 4);
    cvt_kernel<<<(nW2 / 4 + 255) / 256, 256, 0, stream>>>(W2w, wW2, nW2 / 4);
    cvt_kernel<<<(nHead / 4 + 255) / 256, 256, 0, stream>>>(headW, wHead, nHead / 4);
    fold_kernel<<<(nComb + 255) / 256, 256, 0, stream>>>(mWdt, mWx, wComb);

    meanstd_kernel<<<dim3(14, BSZ), 256, 0, stream>>>(x_enc, mean, stdv);
    tok_kernel<<<dim3(28, 16, BSZ), dim3(32, 8), 0, stream>>>(x_enc, x_mark, mean, stdv, t1);
    // embedding: h = tok · W_emb^T + b_emb
    gemm_kernel<128, 0, true, false, false, false, bf><<<dim3(MT, 4), 512, 0, stream>>>(
        t1, nullptr, wEmb, nullptr, h, nullptr, b_emb, nullptr,
        M, DM, SEQ, SEQ, SEQ, 0, DM, 0, 0, 0, 0, 0, nullptr, nullptr);

    for (int l = 0; l < NL; l++) {
        const bf* Winl = wWin + (size_t)l * 2 * 1024 * 512;
        const float* cwl = mcw + (size_t)l * 2 * DM * 2;
        const float* cbl = mcb + (size_t)l * 2 * DM;
        const bf* Combl = wComb + (size_t)l * 2 * 544 * 512;
        const float* bdtl = mbdt + (size_t)l * 2 * DM;
        const float* Alogl = mAlog + (size_t)l * 2 * 512 * 16;
        const float* Dl = mD + (size_t)l * 2 * DM;
        const bf* Woutl = wWout + (size_t)l * 2 * 512 * 512;
        const bf* W1l = wW1 + (size_t)l * DFF * DM;
        const bf* W2l = wW2 + (size_t)l * DM * DFF;

        for (int c = 0; c < NC; c++) {
            size_t coff = (size_t)c * Mc;  // token offset
            // xz = h · [Win_f ; Win_r]^T   (N = 2048)
            gemm_kernel<128, 0, false, false, false, false, bf><<<dim3(MTc, 16), 512, 0, stream>>>(
                h + coff * DM, nullptr, Winl, nullptr, xzc, nullptr, nullptr, nullptr,
                (int)Mc, 2048, 512, 512, 512, 0, 2048, 0, 0, 0, 0, 0, nullptr, nullptr);
            // conv + silu (both directions)
            conv_kernel<<<(int)(2 * Mc * 64 / 256), 256, 0, stream>>>(xzc, cwl, cbl, xcc, (int)Mc);
            // fused dt (softplus -> fp16, N=0..511) + B,C (N=512..543, f32) GEMM
            gemm_kernel<128, 0, true, false, false, true, _Float16><<<dim3(MTc, 5, 2), 512, 0, stream>>>(
                xcc, nullptr, Combl, nullptr, dtcc, dbcc, bdtl, nullptr,
                (int)Mc, 544, 512, 512, 512, 0, 512,
                Mc * 512, (size_t)544 * 512, Mc * 512, Mc * 32, 512, nullptr, nullptr);
            // chunked scan: A (local) -> B (fix) -> C (final, writes y)
            scan_chunk_kernel<false><<<dim3(CB, 2 * NCH), 128, 0, stream>>>(
                dtcc, dbcc, xcc, xzc, Alogl, Dl, hloc, dtsums, ycc, (int)Mc);
            scan_fix_kernel<<<(fixTotal + 255) / 256, 256, 0, stream>>>(hloc, dtsums, Alogl, fixTotal);
            scan_chunk_kernel<true><<<dim3(CB, 2 * NCH), 128, 0, stream>>>(
                dtcc, dbcc, xcc, xzc, Alogl, Dl, hloc, dtsums, ycc, (int)Mc);
            // hsum = h + y_f·Wout_f^T + y_r·Wout_r^T  (K=1024, split at 512)
            gemm_kernel<128, 0, false, true, false, false, bf><<<dim3(MTc, 4), 512, 0, stream>>>(
                ycc, ycc + 512, Woutl, Woutl + 512 * 512, t1 + coff * DM, nullptr, nullptr, h + coff * DM,
                (int)Mc, DM, 1024, 1024, 512, 512, DM, 0, 0, 0, 0, 0, nullptr, nullptr);
        }
        ln_kernel<<<M / 4, 256, 0, stream>>>(t1, t2, ln1g + l * DM, ln1b + l * DM);
        // FFN
        gemm_kernel<128, 1, true, false, false, false, bf><<<dim3(MT, 4), 512, 0, stream>>>(
            t2, nullptr, W1l, nullptr, t1, nullptr, b1w + l * DFF, nullptr,
            M, DFF, DM, DM, DM, 0, DFF, 0, 0, 0, 0, 0, nullptr, nullptr);
        gemm_kernel<128, 0, true, true, false, false, bf><<<dim3(MT, 4), 512, 0, stream>>>(
            t1, nullptr, W2l, nullptr, h, nullptr, b2w + l * DM, t2,
            M, DM, DFF, DFF, DFF, 0, DM, 0, 0, 0, 0, 0, nullptr, nullptr);
        ln_kernel<<<M / 4, 256, 0, stream>>>(h, h, ln2g + l * DM, ln2b + l * DM);
    }

    ln_kernel<<<M / 4, 256, 0, stream>>>(h, t1, lnfg, lnfb);
    // head + de-normalize + scatter to (B, PRED, NVAR), plus loss scalar
    gemm_kernel<128, 0, true, false, true, false, float><<<dim3(MT, 1), 512, 0, stream>>>(
        t1, nullptr, wHead, nullptr, (float*)d_out, nullptr, headb, nullptr,
        M, PRED, DM, DM, DM, 0, 1, 0, 0, 0, 0, 0, mean, stdv);
}

// Round 10
// 3166.108 us; speedup vs baseline: 1.0405x; 1.0405x over previous
//
#include <hip/hip_runtime.h>
#include <hip/hip_bf16.h>
#include <cmath>

typedef __bf16 bf;
typedef _Float16 fp16;
typedef __bf16 bfrag __attribute__((ext_vector_type(8)));
typedef __bf16 bf4 __attribute__((ext_vector_type(4)));
typedef _Float16 h4 __attribute__((ext_vector_type(4)));
typedef float  f32x4 __attribute__((ext_vector_type(4)));

constexpr int BSZ = 32, SEQ = 512, NVAR = 862, NMARK = 4, NTOK = 866;
constexpr int DM = 512, DS = 16, DTR = 32, DFF = 512, NL = 4, PRED = 96;
constexpr int M = BSZ * NTOK;              // 27712 tokens
constexpr float EPS = 1e-5f;
constexpr int NCH = 128, CL = 7;           // chunked scan: 128*7 = 896 >= 866
static_assert(NCH * CL >= NTOK, "chunks must cover sequence");

// async global -> LDS, 16B per lane (wave-uniform LDS base + lane*16)
__device__ __forceinline__ void gload16(const void* g, void* l) {
    __builtin_amdgcn_global_load_lds((const __attribute__((address_space(1))) void*)g,
                                     (__attribute__((address_space(3))) void*)l, 16, 0, 0);
}

// ---------------------------------------------------------------- f32 -> bf16
__global__ void cvt_kernel(const float* __restrict__ src, bf* __restrict__ dst, int n4) {
    int i = blockIdx.x * 256 + threadIdx.x;
    if (i >= n4) return;
    f32x4 v = ((const f32x4*)src)[i];
    bf o[4];
    o[0] = (bf)v[0]; o[1] = (bf)v[1]; o[2] = (bf)v[2]; o[3] = (bf)v[3];
    *(uint2*)&dst[i * 4] = *(uint2*)o;
}

// ---------------- build combined dt/bc weight: [ld][544][512] bf16
// rows 0..511: Fold = Wdt(512x32)·Wx[0:32]  ;  rows 512..543: Wx[32:64] (B,C)
__global__ void fold_kernel(const float* __restrict__ Wdt, const float* __restrict__ Wx,
                            bf* __restrict__ out) {
    int idx = blockIdx.x * 256 + threadIdx.x;     // NL*2*544*512 total
    int k = idx & 511; int rest = idx >> 9;
    int row = rest % 544; int ld = rest / 544;
    float s;
    if (row < 512) {
        const float* wd = Wdt + ((size_t)ld * 512 + row) * 32;
        const float* wx = Wx + (size_t)ld * 64 * 512 + k;
        s = 0.f;
#pragma unroll 8
        for (int r = 0; r < 32; r++) s += wd[r] * wx[(size_t)r * 512];
    } else {
        s = Wx[(size_t)ld * 64 * 512 + (size_t)(32 + row - 512) * 512 + k];
    }
    out[((size_t)ld * 544 + row) * 512 + k] = (bf)s;
}

// ---------------- per-channel A20 / fast-flag precompute (once per forward)
// A20[ldd] = -exp(Alog[ldd][0])*log2e ; LC[ldd] = 1 if A2[s] == (s+1)*A20
// (the per-chunk scan prologue was 64 expf per thread -- now 2 vector loads).
__global__ void a20_kernel(const float* __restrict__ Alog, float* __restrict__ a20,
                           float* __restrict__ lcf, int total) {
    int i = blockIdx.x * 256 + threadIdx.x;    // NL*2*512
    if (i >= total) return;
    constexpr float L2E = 1.4426950408889634f;
    const float* ap = Alog + (size_t)i * DS;
    float a0 = -__expf(ap[0]) * L2E;
    bool lc = true;
#pragma unroll
    for (int s = 1; s < 16; s++) {
        float as = -__expf(ap[s]) * L2E;
        lc = lc && (fabsf(as - (s + 1) * a0) <= 1e-4f * fabsf(as));
    }
    a20[i] = a0;
    lcf[i] = lc ? 1.f : 0.f;
}

// ---------------------------------------------------------------- mean / std
__global__ __launch_bounds__(256) void meanstd_kernel(const float* __restrict__ xe,
                               float* __restrict__ mean, float* __restrict__ stdv) {
    __shared__ float sm[2][4][64];
    int b = blockIdx.y;
    int vl = threadIdx.x & 63;
    int tg = threadIdx.x >> 6;
    int v = blockIdx.x * 64 + vl;
    float s = 0.f, sq = 0.f;
    if (v < NVAR) {
        const float* p = xe + (size_t)b * SEQ * NVAR + (size_t)tg * 128 * NVAR + v;
#pragma unroll 4
        for (int t = 0; t < 128; t++) {
            float x = p[(size_t)t * NVAR];
            s += x; sq += x * x;
        }
    }
    sm[0][tg][vl] = s; sm[1][tg][vl] = sq;
    __syncthreads();
    if (tg == 0 && v < NVAR) {
        s  = sm[0][0][vl] + sm[0][1][vl] + sm[0][2][vl] + sm[0][3][vl];
        sq = sm[1][0][vl] + sm[1][1][vl] + sm[1][2][vl] + sm[1][3][vl];
        float mu = s * (1.f / SEQ);
        float var = sq * (1.f / SEQ) - mu * mu;
        mean[b * NVAR + v] = mu;
        stdv[b * NVAR + v] = sqrtf(var + EPS);
    }
}

// ------------------------------------------------- tok build (transpose+norm)
__global__ void tok_kernel(const float* __restrict__ xe, const float* __restrict__ xm,
                           const float* __restrict__ mean, const float* __restrict__ stdv,
                           bf* __restrict__ tok) {
    __shared__ float tile[32][33];
    int b = blockIdx.z;
    int v0 = blockIdx.x * 32, s0 = blockIdx.y * 32;
    int tx = threadIdx.x, ty = threadIdx.y;  // 32 x 8
    int v = v0 + tx;
    float mu = 0.f, rs = 0.f;
    if (v < NVAR) { mu = mean[b * NVAR + v]; rs = 1.f / stdv[b * NVAR + v]; }
#pragma unroll
    for (int j = 0; j < 4; j++) {
        int s = s0 + ty + j * 8;
        float val = 0.f;
        if (v < NVAR)       val = (xe[((size_t)b * SEQ + s) * NVAR + v] - mu) * rs;
        else if (v < NTOK)  val = xm[((size_t)b * SEQ + s) * NMARK + (v - NVAR)];
        tile[ty + j * 8][tx] = val;
    }
    __syncthreads();
#pragma unroll
    for (int j = 0; j < 4; j++) {
        int n = v0 + ty + j * 8;
        if (n < NTOK)
            tok[((size_t)b * NTOK + n) * SEQ + s0 + tx] = (bf)tile[tx][ty + j * 8];
    }
}

// ---------------------------------------------------------------- GEMM
// C[M,N] = A[M,K](bf16) * W[N,K]^T (bf16), f32 accumulate.
// 64x128 tile, 8 waves / 512 threads; each wave owns 32x32 output (acc = 16
// VGPR). LDS = 48 KB double-buffered -> 3 blocks/CU. Counted-vmcnt pipeline.
// DTBC: dt output stored as fp16 (CT=_Float16), B/C as f32 to C2.
template <int BN, int ACT, bool BIAS, bool RES, bool HEAD, bool DTBC, typename CT>
__global__ __launch_bounds__(512, 6) void gemm_kernel(
    const bf* __restrict__ A0, const bf* __restrict__ A1,
    const bf* __restrict__ W0, const bf* __restrict__ W1,
    CT* __restrict__ C, float* __restrict__ C2,
    const float* __restrict__ bias, const bf* __restrict__ res,
    int Mreal, int Nreal, int K, int lda, int ldw, int ksplit, int ldc,
    size_t sAz, size_t sWz, size_t sCz, size_t sC2z, size_t sBiasz,
    const float* __restrict__ mean, const float* __restrict__ stdv) {
    constexpr int BM = 64, BK = 64;
    static_assert(BN == 128, "8-wave layout assumes 64x128 tile");
    __shared__ __align__(16) bf Als[2][BM * BK];
    __shared__ __align__(16) bf Bls[2][BN * BK];

    // ---- XCD-chunked bijective remap (m204 formula), n fastest within m ----
    int gx = gridDim.x, gy = gridDim.y;
    int gxy = gx * gy;
    int nbt = gxy * gridDim.z;
    int id = blockIdx.x + gx * (blockIdx.y + gy * blockIdx.z);
    int q8 = nbt >> 3, r8 = nbt & 7;
    int xcd = id & 7, rank = id >> 3;
    int w = xcd * q8 + (xcd < r8 ? xcd : r8) + rank;
    int z = w / gxy;
    int rem = w - z * gxy;
    int m0 = (rem / gy) * BM;
    int n0 = (rem % gy) * BN;

    A0 += (size_t)z * sAz; W0 += (size_t)z * sWz; C += (size_t)z * sCz;
    if (DTBC) C2 += (size_t)z * sC2z;
    if (BIAS) bias += (size_t)z * sBiasz;
    int tid = threadIdx.x, lane = tid & 63, wave = tid >> 6;   // 0..7
    int wm = wave >> 2, wn = wave & 3;        // 2 row-halves x 4 col-quarters
    int q = lane >> 4, ml = lane & 15;
    int srow = lane >> 3;
    int aswz = ((lane & 7) ^ srow) * 8;          // global col offset (elems)
    int swz = ((q ^ (ml & 7))) * 8;

    f32x4 acc[2][2];
#pragma unroll
    for (int i = 0; i < 2; i++)
#pragma unroll
        for (int j = 0; j < 2; j++) { acc[i][j][0] = 0.f; acc[i][j][1] = 0.f; acc[i][j][2] = 0.f; acc[i][j][3] = 0.f; }

    // per-wave: 3 async loads per stage (1 A row-group + 2 B row-groups)
    auto stage = [&](int kt, int buf) {
        const bf* ab = (ksplit && kt >= ksplit) ? (A1 + (kt - ksplit)) : (A0 + kt);
        const bf* wb = (ksplit && kt >= ksplit) ? (W1 + (kt - ksplit)) : (W0 + kt);
        {
            int r = wave * 8;                  // 8 waves x 8 rows = 64 A rows
            gload16(ab + (size_t)(m0 + r + srow) * lda + aswz, &Als[buf][r * BK]);
        }
#pragma unroll
        for (int i = 0; i < 2; i++) {
            int r = wave * 16 + i * 8;         // 8 waves x 16 rows = 128 B rows
            gload16(wb + (size_t)(n0 + r + srow) * ldw + aswz, &Bls[buf][r * BK]);
        }
    };

    stage(0, 0);
    int cur = 0;
    for (int kt = 0; kt < K; kt += BK) {
        bool pf = (kt + BK < K);
        if (pf) stage(kt + BK, cur ^ 1);       // prefetch next tile (3 loads)
        if (pf) asm volatile("s_waitcnt vmcnt(3)" ::: "memory");
        else    asm volatile("s_waitcnt vmcnt(0)" ::: "memory");
        __builtin_amdgcn_s_barrier();           // all waves' tile-t data in LDS
        __builtin_amdgcn_sched_barrier(0);      // pin LDS reads after barrier
#pragma unroll
        for (int kk = 0; kk < BK; kk += 32) {
            bfrag af[2], bff[2];
#pragma unroll
            for (int i = 0; i < 2; i++)
                af[i] = *(bfrag*)&Als[cur][(wm * 32 + i * 16 + ml) * BK + (swz ^ kk)];
#pragma unroll
            for (int j = 0; j < 2; j++)
                bff[j] = *(bfrag*)&Bls[cur][(wn * 32 + j * 16 + ml) * BK + (swz ^ kk)];
#pragma unroll
            for (int i = 0; i < 2; i++)
#pragma unroll
                for (int j = 0; j < 2; j++)
                    acc[i][j] = __builtin_amdgcn_mfma_f32_16x16x32_bf16(bff[j], af[i], acc[i][j], 0, 0, 0);
        }
        __builtin_amdgcn_sched_barrier(0);      // pin LDS reads before barrier
        __builtin_amdgcn_s_barrier();           // all waves done reading cur
        cur ^= 1;
    }

    // epilogue: acc[i][j][r] -> row = m0+wm*32+i*16+ml ; col = n0+wn*32+j*16+q*4+r
#pragma unroll
    for (int i = 0; i < 2; i++) {
        int row = m0 + wm * 32 + i * 16 + ml;
        if (row >= Mreal) continue;
#pragma unroll
        for (int j = 0; j < 2; j++) {
            int colb = n0 + wn * 32 + j * 16 + q * 4;
            if (colb >= Nreal) continue;          // N multiples of 4 -> whole quad in/out
            f32x4 x = acc[i][j];
            if constexpr (BIAS) {
                if (!DTBC || colb < 512) {
                    f32x4 bv = *(const f32x4*)&bias[colb];
#pragma unroll
                    for (int r = 0; r < 4; r++) x[r] += bv[r];
                }
            }
            if constexpr (DTBC) {
                if (colb < 512) {
                    h4 hv;
#pragma unroll
                    for (int r = 0; r < 4; r++) {
                        float xs = (x[r] > 20.f) ? x[r] : __logf(1.f + __expf(x[r]));  // softplus
                        hv[r] = (_Float16)xs;
                    }
                    *(h4*)&C[(size_t)row * 512 + colb] = hv;        // CT=_Float16
                } else {
                    *(f32x4*)&C2[(size_t)row * 32 + (colb - 512)] = x;
                }
            } else {
                if constexpr (ACT == 1) {
#pragma unroll
                    for (int r = 0; r < 4; r++)
                        x[r] = 0.5f * x[r] * (1.f + erff(x[r] * 0.70710678118654752f));
                }
                if constexpr (RES) {
                    bf4 rv = *(const bf4*)&res[(size_t)row * DM + colb];
#pragma unroll
                    for (int r = 0; r < 4; r++) x[r] += (float)rv[r];
                }
                if constexpr (HEAD) {
                    int bidx = row / NTOK, n = row - bidx * NTOK;
                    if (n < NVAR) {
                        float sc = stdv[bidx * NVAR + n], mm = mean[bidx * NVAR + n];
#pragma unroll
                        for (int r = 0; r < 4; r++) {
                            int col = colb + r;
                            if (col < Nreal)
                                C[((size_t)bidx * PRED + col) * NVAR + n] = (CT)(x[r] * sc + mm);
                        }
                    }
                } else {
                    bf4 ov;
#pragma unroll
                    for (int r = 0; r < 4; r++) ov[r] = (bf)x[r];
                    *(bf4*)&C[(size_t)row * ldc + colb] = ov;
                }
            }
        }
    }
    if (HEAD && blockIdx.x == 0 && blockIdx.y == 0 && blockIdx.z == 0 && tid == 0)
        C[(size_t)BSZ * PRED * NVAR] = (CT)0.f;  // loss_reg = 0
}

// ---------------------------------------------------------------- conv + silu
__global__ void conv_kernel(const bf* __restrict__ xz, const float* __restrict__ cw,
                            const float* __restrict__ cb, bf* __restrict__ xc, int Mc) {
    int id = blockIdx.x * 256 + threadIdx.x;   // 2*Mc*64 total
    int dir = id / (Mc * 64); int rem = id - dir * (Mc * 64);
    int token = rem >> 6; int ch0 = (rem & 63) * 8;
    int t = token % NTOK;
    const bf* xb = xz + (size_t)token * (4 * DM) + dir * (2 * DM) + ch0;
    bfrag xt = *(const bfrag*)xb;
    bfrag xn;
#pragma unroll
    for (int i = 0; i < 8; i++) xn[i] = (bf)0.f;
    int tn = dir ? t + 1 : t - 1;
    if ((unsigned)tn < (unsigned)NTOK)
        xn = *(const bfrag*)(xb + (dir ? (4 * DM) : -(4 * DM)));
    const float2* cwp = (const float2*)cw + ((size_t)dir * DM + ch0);
    const float*  cbp = cb + (size_t)dir * DM + ch0;
    bfrag ov;
#pragma unroll
    for (int jj = 0; jj < 8; jj++) {
        float2 w = cwp[jj];
        float x = (float)xn[jj] * w.x + (float)xt[jj] * w.y + cbp[jj];
        x = x / (1.f + __expf(-x));
        ov[jj] = (bf)x;
    }
    *(bfrag*)(xc + (size_t)dir * Mc * DM + (size_t)token * DM + ch0) = ov;
}

// ---------------------------------------------------------------- chunked scan
// Packed: each lane owns 4 consecutive channels (8B vector global ops, LDS
// broadcast amortized 4x, 4-way ILP). NCH=128 (CL=7): 4096 waves = 4/SIMD
// (exactly the 120-VGPR residency cap) -- R9 showed the packed kernel is
// latency-bound and scales with resident waves. The per-chunk A2/fast
// prologue (was 64 expf/thread -- dominant at CL=7) is replaced by 2 vector
// loads of precomputed A20/LC (a20_kernel).
template <bool FINAL>
__global__ __launch_bounds__(128, 2) void scan_chunk_kernel(
    const fp16* __restrict__ dtc, const float* __restrict__ dbc,
    const bf* __restrict__ xc, const bf* __restrict__ xz,
    const float* __restrict__ Alog, const float* __restrict__ A20g,
    const float* __restrict__ LCg, const float* __restrict__ Dp,
    float* __restrict__ hloc, float* __restrict__ dtsums,
    bf* __restrict__ y, int Mc) {
    __shared__ __align__(16) float row[2][32];
    int wid = threadIdx.x >> 6;                // cg: channel group 0/1
    int lane = threadIdx.x & 63;
    int b = blockIdx.x;
    int zc = blockIdx.y; int dir = zc / NCH, c = zc - dir * NCH;
    int d0 = wid * 256 + lane * 4;             // 4 consecutive channels
    int dd0 = dir * DM + d0;

    constexpr float L2E = 1.4426950408889634f;
    f32x4 a20v = *(const f32x4*)&A20g[dd0];
    f32x4 lcv  = *(const f32x4*)&LCg[dd0];
    float A20[4];
#pragma unroll
    for (int cc = 0; cc < 4; cc++) A20[cc] = a20v[cc];
    bool lc = (lcv[0] + lcv[1] + lcv[2] + lcv[3]) == 4.f;
    bool fast = (__ballot(lc) == ~0ull);
    float Dd[4];
#pragma unroll
    for (int cc = 0; cc < 4; cc++) Dd[cc] = FINAL ? Dp[dd0 + cc] : 0.f;

    const size_t hbase = ((size_t)(b * 2 + dir) * NCH + c) * 8192;   // 16*512
    float h[4][16];
    if (FINAL) {
#pragma unroll
        for (int s = 0; s < 16; s++) {
            f32x4 hv = *(const f32x4*)&hloc[hbase + (size_t)s * 512 + d0];
#pragma unroll
            for (int cc = 0; cc < 4; cc++) h[cc][s] = hv[cc];
        }
    } else {
#pragma unroll
        for (int cc = 0; cc < 4; cc++)
#pragma unroll
            for (int s = 0; s < 16; s++) h[cc][s] = 0.f;
    }
    float dtsum[4] = {0.f, 0.f, 0.f, 0.f};

    const int t0 = c * CL;
    const int t1e = (t0 + CL < NTOK) ? t0 + CL : NTOK;
    const long step = dir ? -1 : 1;

    const fp16* dtp = nullptr; const float* bcp = nullptr;
    const bf* xcp = nullptr; const bf* xzp = nullptr; bf* yp = nullptr;
    h4 dtq = {(_Float16)0.f, (_Float16)0.f, (_Float16)0.f, (_Float16)0.f};
    bf4 xq; bf4 zq;
#pragma unroll
    for (int cc = 0; cc < 4; cc++) { xq[cc] = (bf)0.f; zq[cc] = (bf)0.f; }
    f32x4 gq = {0.f, 0.f, 0.f, 0.f};
    if (t0 < t1e) {
        long tok0 = (long)b * NTOK + (dir ? (NTOK - 1 - t0) : t0);
        dtp = dtc + (size_t)dir * Mc * 512 + (size_t)tok0 * 512 + d0;
        bcp = dbc + ((size_t)dir * Mc + (size_t)tok0) * 32;
        xcp = xc + (size_t)dir * Mc * 512 + (size_t)tok0 * 512 + d0;
        dtq = *(const h4*)dtp;
        if (lane < 8) gq = ((const f32x4*)bcp)[lane];
        xq = *(const bf4*)xcp;
        if (FINAL) {
            xzp = xz + (size_t)tok0 * 2048 + dir * 1024 + 512 + d0;
            yp  = y  + (size_t)tok0 * 1024 + dir * 512 + d0;
            zq = *(const bf4*)xzp;
        }
    }
    const long sdt = step * 512, sbc = step * 32, sxc = step * 512;
    const long sxz = step * 2048, sy = step * 1024;

    for (int t = t0; t < t1e; t++) {
        if (lane < 8) ((f32x4*)row[wid])[lane] = gq;
        float dtv[4], xv[4], zv[4], dtx[4];
#pragma unroll
        for (int cc = 0; cc < 4; cc++) {
            dtv[cc] = (float)dtq[cc];
            xv[cc] = (float)xq[cc];
            if (FINAL) zv[cc] = (float)zq[cc];
            dtx[cc] = dtv[cc] * xv[cc];
            dtsum[cc] += dtv[cc];
        }
        bf* ypc = yp;
        if (t + 1 < t1e) {                     // prefetch next token
            dtp += sdt; bcp += sbc; xcp += sxc;
            dtq = *(const h4*)dtp;
            if (lane < 8) gq = ((const f32x4*)bcp)[lane];
            xq = *(const bf4*)xcp;
            if (FINAL) { xzp += sxz; zq = *(const bf4*)xzp; yp += sy; }
        }
        const f32x4* rv = (const f32x4*)row[wid];
        float yva[4] = {0.f, 0.f, 0.f, 0.f};
        if (fast) {
            float r[4], r2[4], r3[4], r4[4], bse[4];
#pragma unroll
            for (int cc = 0; cc < 4; cc++) {
                r[cc] = exp2f(dtv[cc] * A20[cc]);
                r2[cc] = r[cc] * r[cc]; r3[cc] = r2[cc] * r[cc]; r4[cc] = r2[cc] * r2[cc];
                bse[cc] = r[cc];
            }
#pragma unroll
            for (int i = 0; i < 4; i++) {
                f32x4 Bv = rv[i];
                f32x4 Cv = rv[4 + i];
#pragma unroll
                for (int cc = 0; cc < 4; cc++) {
                    int s = i * 4;
                    float p0 = bse[cc], p1 = p0 * r[cc], p2 = p0 * r2[cc], p3 = p0 * r3[cc];
                    h[cc][s + 0] = p0 * h[cc][s + 0] + dtx[cc] * Bv[0];
                    h[cc][s + 1] = p1 * h[cc][s + 1] + dtx[cc] * Bv[1];
                    h[cc][s + 2] = p2 * h[cc][s + 2] + dtx[cc] * Bv[2];
                    h[cc][s + 3] = p3 * h[cc][s + 3] + dtx[cc] * Bv[3];
                    if (FINAL)
                        yva[cc] += Cv[0] * h[cc][s + 0] + Cv[1] * h[cc][s + 1]
                                 + Cv[2] * h[cc][s + 2] + Cv[3] * h[cc][s + 3];
                    bse[cc] *= r4[cc];
                }
            }
        } else {
            // slow path (never taken for this model's Alog; kept for correctness)
#pragma unroll
            for (int i = 0; i < 4; i++) {
                f32x4 Bv = rv[i];
                f32x4 Cv = rv[4 + i];
#pragma unroll
                for (int cc = 0; cc < 4; cc++) {
#pragma unroll
                    for (int jj = 0; jj < 4; jj++) {
                        int s = i * 4 + jj;
                        float A2 = -__expf(Alog[(size_t)(dd0 + cc) * DS + s]) * L2E;
                        float a = exp2f(dtv[cc] * A2);
                        h[cc][s] = a * h[cc][s] + dtx[cc] * Bv[jj];
                        if (FINAL) yva[cc] += Cv[jj] * h[cc][s];
                    }
                }
            }
        }
        if (FINAL) {
            bf4 ov;
#pragma unroll
            for (int cc = 0; cc < 4; cc++) {
                float sz = zv[cc] / (1.f + __expf(-zv[cc]));
                ov[cc] = (bf)((yva[cc] + Dd[cc] * xv[cc]) * sz);
            }
            *(bf4*)ypc = ov;
        }
    }
    if (!FINAL) {
#pragma unroll
        for (int s = 0; s < 16; s++) {
            f32x4 hv;
#pragma unroll
            for (int cc = 0; cc < 4; cc++) hv[cc] = h[cc][s];
            *(f32x4*)&hloc[hbase + (size_t)s * 512 + d0] = hv;
        }
        f32x4 dv;
#pragma unroll
        for (int cc = 0; cc < 4; cc++) dv[cc] = dtsum[cc];
        *(f32x4*)&dtsums[((size_t)(b * 2 + dir) * NCH + c) * 512 + d0] = dv;
    }
}

// Phase B: combine chunk summaries (serial over NCH chunks per group).
// hloc layout [g][c][s][d]; dtsums [g][c][d]. One thread per (g,s,d):
// coalesced on d. aprod = exp2(dtsum * A2[s]) computed on the fly.
__global__ void scan_fix_kernel(float* __restrict__ hloc, const float* __restrict__ dtsums,
                                const float* __restrict__ Alog, int total) {
    int tid = blockIdx.x * 256 + threadIdx.x;
    if (tid >= total) return;
    int d = tid & 511;
    int s = (tid >> 9) & 15;
    int g = tid >> 13;                 // b*2+dir
    int dir = g & 1;
    float A2s = -__expf(Alog[((size_t)(dir * DM + d)) * DS + s]) * 1.4426950408889634f;
    size_t i0 = (size_t)g * NCH * 8192 + (size_t)s * 512 + d;
    size_t d0 = (size_t)g * NCH * 512 + d;
    float H = 0.f;
#pragma unroll 8
    for (int c = 0; c < NCH; c++) {
        size_t ix = i0 + (size_t)c * 8192;
        float hl = hloc[ix];
        float ap = exp2f(dtsums[d0 + (size_t)c * 512] * A2s);
        hloc[ix] = H;
        H = hl + ap * H;
    }
}

// ---------------------------------------------------------------- LayerNorm
__global__ __launch_bounds__(256) void ln_kernel(const bf* X, bf* Y,
                                                 const float* __restrict__ g, const float* __restrict__ bb) {
    int token = blockIdx.x * 4 + (threadIdx.x >> 6);
    int lane = threadIdx.x & 63;
    bfrag xv = *(const bfrag*)(X + (size_t)token * DM + lane * 8);
    float xf[8]; float s = 0.f, sq = 0.f;
#pragma unroll
    for (int j = 0; j < 8; j++) { xf[j] = (float)xv[j]; s += xf[j]; sq += xf[j] * xf[j]; }
#pragma unroll
    for (int o = 1; o < 64; o <<= 1) { s += __shfl_xor(s, o); sq += __shfl_xor(sq, o); }
    float mu = s * (1.f / DM);
    float rs = rsqrtf(sq * (1.f / DM) - mu * mu + EPS);
    f32x4 g0 = ((const f32x4*)g)[lane * 2], g1 = ((const f32x4*)g)[lane * 2 + 1];
    f32x4 b0 = ((const f32x4*)bb)[lane * 2], b1 = ((const f32x4*)bb)[lane * 2 + 1];
    bfrag ov;
#pragma unroll
    for (int j = 0; j < 8; j++) {
        float gg = (j < 4) ? g0[j] : g1[j - 4];
        float bbv = (j < 4) ? b0[j] : b1[j - 4];
        ov[j] = (bf)((xf[j] - mu) * rs * gg + bbv);
    }
    *(bfrag*)(Y + (size_t)token * DM + lane * 8) = ov;
}

// ---------------------------------------------------------------- launch
extern "C" void kernel_launch(void* const* d_in, const int* in_sizes, int n_in,
                              void* d_out, int out_size, void* d_ws, size_t ws_size,
                              hipStream_t stream) {
    const float* x_enc = (const float*)d_in[0];
    const float* x_mark = (const float*)d_in[1];
    const float* W_emb = (const float*)d_in[4];
    const float* b_emb = (const float*)d_in[5];
    const float* mWin = (const float*)d_in[6];
    const float* mcw = (const float*)d_in[7];
    const float* mcb = (const float*)d_in[8];
    const float* mWx = (const float*)d_in[9];
    const float* mWdt = (const float*)d_in[10];
    const float* mbdt = (const float*)d_in[11];
    const float* mAlog = (const float*)d_in[12];
    const float* mD = (const float*)d_in[13];
    const float* mWout = (const float*)d_in[14];
    const float* W1w = (const float*)d_in[15];
    const float* b1w = (const float*)d_in[16];
    const float* W2w = (const float*)d_in[17];
    const float* b2w = (const float*)d_in[18];
    const float* ln1g = (const float*)d_in[19];
    const float* ln1b = (const float*)d_in[20];
    const float* ln2g = (const float*)d_in[21];
    const float* ln2b = (const float*)d_in[22];
    const float* lnfg = (const float*)d_in[23];
    const float* lnfb = (const float*)d_in[24];
    const float* headW = (const float*)d_in[25];
    const float* headb = (const float*)d_in[26];

    auto a256 = [](size_t x) { return (x + 255) & ~(size_t)255; };
    char* ws = (char*)d_ws;
    size_t off = 0;
    auto alloc = [&](size_t n) { size_t r = off; off += a256(n); return ws + r; };
    float* mean = (float*)alloc((size_t)BSZ * NVAR * 4);
    float* stdv = (float*)alloc((size_t)BSZ * NVAR * 4);
    bf* h  = (bf*)alloc((size_t)M * DM * 2);
    bf* t1 = (bf*)alloc((size_t)M * DM * 2);   // tok / hsum / ff
    bf* t2 = (bf*)alloc((size_t)M * DM * 2);   // h2
    // bf16-converted GEMM weights
    constexpr int nEmb = 512 * 512, nWin = NL * 2 * 1024 * 512,
                  nWout = NL * 2 * 512 * 512, nW1 = NL * DFF * DM, nW2 = NL * DM * DFF,
                  nHead = PRED * DM, nComb = NL * 2 * 544 * 512;
    bf* wEmb  = (bf*)alloc((size_t)nEmb * 2);
    bf* wWin  = (bf*)alloc((size_t)nWin * 2);
    bf* wWout = (bf*)alloc((size_t)nWout * 2);
    bf* wW1   = (bf*)alloc((size_t)nW1 * 2);
    bf* wW2   = (bf*)alloc((size_t)nW2 * 2);
    bf* wHead = (bf*)alloc((size_t)nHead * 2);
    bf* wComb = (bf*)alloc((size_t)nComb * 2);
    float* aA20 = (float*)alloc((size_t)NL * 2 * 512 * 4);   // precomputed A20
    float* aLC  = (float*)alloc((size_t)NL * 2 * 512 * 4);   // fast flags
    size_t fixedEnd = off;

    // adaptive chunk size: CB batches per chunk
    auto scanScr = [&](size_t cb) { return cb * 2 * (size_t)NCH * 8192 * 4; };  // hloc
    auto dtsScr  = [&](size_t cb) { return cb * 2 * (size_t)NCH * 512 * 4; };   // dtsums
    int CB = 1;
    {
        int cbs[6] = {32, 16, 8, 4, 2, 1};
        for (int i = 0; i < 6; i++) {
            size_t mc = (size_t)cbs[i] * NTOK;
            size_t chunkB = a256(mc * 4096) + a256(mc * 2048) + a256(mc * 256)
                          + a256(mc * 2048) + a256(mc * 2048)
                          + a256(scanScr(cbs[i])) + a256(dtsScr(cbs[i]));
            if (fixedEnd + chunkB <= ws_size) { CB = cbs[i]; break; }
        }
    }
    const size_t Mc = (size_t)CB * NTOK;
    size_t co = fixedEnd;
    bf* xzc = (bf*)(ws + co);        co += a256(Mc * 4096);
    bf* xcc = (bf*)(ws + co);        co += a256(Mc * 2048);
    float* dbcc = (float*)(ws + co); co += a256(Mc * 256);
    bf* ycc = (bf*)(ws + co);        co += a256(Mc * 2048);
    fp16* dtcc = (fp16*)(ws + co);   co += a256(Mc * 2048);   // fp16, 2 dirs x 512
    float* hloc = (float*)(ws + co); co += a256(scanScr(CB));
    float* dtsums = (float*)(ws + co);
    const int NC = BSZ / CB;
    const int MTc = (int)((Mc + 63) / 64);     // BM=64 m-panels
    constexpr int MT = (M + 63) / 64;          // 433 (exact: 27712 = 433*64)
    const int fixTotal = CB * 2 * 16 * 512;

    // weight conversion f32 -> bf16, combined dt/bc weight, A20 precompute
    cvt_kernel<<<(nEmb / 4 + 255) / 256, 256, 0, stream>>>(W_emb, wEmb, nEmb / 4);
    cvt_kernel<<<(nWin / 4 + 255) / 256, 256, 0, stream>>>(mWin, wWin, nWin / 4);
    cvt_kernel<<<(nWout / 4 + 255) / 256, 256, 0, stream>>>(mWout, wWout, nWout / 4);
    cvt_kernel<<<(nW1 / 4 + 255) / 256, 256, 0, stream>>>(W1w, wW1, nW1 / 4);
    cvt_kernel<<<(nW2 / 4 + 255) / 256, 256, 0, stream>>>(W2w, wW2, nW2 / 4);
    cvt_kernel<<<(nHead / 4 + 255) / 256, 256, 0, stream>>>(headW, wHead, nHead / 4);
    fold_kernel<<<(nComb + 255) / 256, 256, 0, stream>>>(mWdt, mWx, wComb);
    a20_kernel<<<(NL * 2 * 512 + 255) / 256, 256, 0, stream>>>(mAlog, aA20, aLC, NL * 2 * 512);

    meanstd_kernel<<<dim3(14, BSZ), 256, 0, stream>>>(x_enc, mean, stdv);
    tok_kernel<<<dim3(28, 16, BSZ), dim3(32, 8), 0, stream>>>(x_enc, x_mark, mean, stdv, t1);
    // embedding: h = tok · W_emb^T + b_emb
    gemm_kernel<128, 0, true, false, false, false, bf><<<dim3(MT, 4), 512, 0, stream>>>(
        t1, nullptr, wEmb, nullptr, h, nullptr, b_emb, nullptr,
        M, DM, SEQ, SEQ, SEQ, 0, DM, 0, 0, 0, 0, 0, nullptr, nullptr);

    for (int l = 0; l < NL; l++) {
        const bf* Winl = wWin + (size_t)l * 2 * 1024 * 512;
        const float* cwl = mcw + (size_t)l * 2 * DM * 2;
        const float* cbl = mcb + (size_t)l * 2 * DM;
        const bf* Combl = wComb + (size_t)l * 2 * 544 * 512;
        const float* bdtl = mbdt + (size_t)l * 2 * DM;
        const float* Alogl = mAlog + (size_t)l * 2 * 512 * 16;
        const float* A20l = aA20 + (size_t)l * 2 * 512;
        const float* LCl  = aLC  + (size_t)l * 2 * 512;
        const float* Dl = mD + (size_t)l * 2 * DM;
        const bf* Woutl = wWout + (size_t)l * 2 * 512 * 512;
        const bf* W1l = wW1 + (size_t)l * DFF * DM;
        const bf* W2l = wW2 + (size_t)l * DM * DFF;

        for (int c = 0; c < NC; c++) {
            size_t coff = (size_t)c * Mc;  // token offset
            // xz = h · [Win_f ; Win_r]^T   (N = 2048)
            gemm_kernel<128, 0, false, false, false, false, bf><<<dim3(MTc, 16), 512, 0, stream>>>(
                h + coff * DM, nullptr, Winl, nullptr, xzc, nullptr, nullptr, nullptr,
                (int)Mc, 2048, 512, 512, 512, 0, 2048, 0, 0, 0, 0, 0, nullptr, nullptr);
            // conv + silu (both directions)
            conv_kernel<<<(int)(2 * Mc * 64 / 256), 256, 0, stream>>>(xzc, cwl, cbl, xcc, (int)Mc);
            // fused dt (softplus -> fp16, N=0..511) + B,C (N=512..543, f32) GEMM
            gemm_kernel<128, 0, true, false, false, true, _Float16><<<dim3(MTc, 5, 2), 512, 0, stream>>>(
                xcc, nullptr, Combl, nullptr, dtcc, dbcc, bdtl, nullptr,
                (int)Mc, 544, 512, 512, 512, 0, 512,
                Mc * 512, (size_t)544 * 512, Mc * 512, Mc * 32, 512, nullptr, nullptr);
            // chunked scan: A (local) -> B (fix) -> C (final, writes y)
            scan_chunk_kernel<false><<<dim3(CB, 2 * NCH), 128, 0, stream>>>(
                dtcc, dbcc, xcc, xzc, Alogl, A20l, LCl, Dl, hloc, dtsums, ycc, (int)Mc);
            scan_fix_kernel<<<(fixTotal + 255) / 256, 256, 0, stream>>>(hloc, dtsums, Alogl, fixTotal);
            scan_chunk_kernel<true><<<dim3(CB, 2 * NCH), 128, 0, stream>>>(
                dtcc, dbcc, xcc, xzc, Alogl, A20l, LCl, Dl, hloc, dtsums, ycc, (int)Mc);
            // hsum = h + y_f·Wout_f^T + y_r·Wout_r^T  (K=1024, split at 512)
            gemm_kernel<128, 0, false, true, false, false, bf><<<dim3(MTc, 4), 512, 0, stream>>>(
                ycc, ycc + 512, Woutl, Woutl + 512 * 512, t1 + coff * DM, nullptr, nullptr, h + coff * DM,
                (int)Mc, DM, 1024, 1024, 512, 512, DM, 0, 0, 0, 0, 0, nullptr, nullptr);
        }
        ln_kernel<<<M / 4, 256, 0, stream>>>(t1, t2, ln1g + l * DM, ln1b + l * DM);
        // FFN
        gemm_kernel<128, 1, true, false, false, false, bf><<<dim3(MT, 4), 512, 0, stream>>>(
            t2, nullptr, W1l, nullptr, t1, nullptr, b1w + l * DFF, nullptr,
            M, DFF, DM, DM, DM, 0, DFF, 0, 0, 0, 0, 0, nullptr, nullptr);
        gemm_kernel<128, 0, true, true, false, false, bf><<<dim3(MT, 4), 512, 0, stream>>>(
            t1, nullptr, W2l, nullptr, h, nullptr, b2w + l * DM, t2,
            M, DM, DFF, DFF, DFF, 0, DM, 0, 0, 0, 0, 0, nullptr, nullptr);
        ln_kernel<<<M / 4, 256, 0, stream>>>(h, h, ln2g + l * DM, ln2b + l * DM);
    }

    ln_kernel<<<M / 4, 256, 0, stream>>>(h, t1, lnfg, lnfb);
    // head + de-normalize + scatter to (B, PRED, NVAR), plus loss scalar
    gemm_kernel<128, 0, true, false, true, false, float><<<dim3(MT, 1), 512, 0, stream>>>(
        t1, nullptr, wHead, nullptr, (float*)d_out, nullptr, headb, nullptr,
        M, PRED, DM, DM, DM, 0, 1, 0, 0, 0, 0, 0, mean, stdv);
}

// Round 11
// 2509.190 us; speedup vs baseline: 1.3129x; 1.2618x over previous
//
#include <hip/hip_runtime.h>
#include <hip/hip_bf16.h>
#include <cmath>

typedef __bf16 bf;
typedef _Float16 fp16;
typedef __bf16 bfrag __attribute__((ext_vector_type(8)));
typedef __bf16 bf4 __attribute__((ext_vector_type(4)));
typedef _Float16 h4 __attribute__((ext_vector_type(4)));
typedef float  f32x4 __attribute__((ext_vector_type(4)));

constexpr int BSZ = 32, SEQ = 512, NVAR = 862, NMARK = 4, NTOK = 866;
constexpr int DM = 512, DS = 16, DTR = 32, DFF = 512, NL = 4, PRED = 96;
constexpr int M = BSZ * NTOK;              // 27712 tokens
constexpr float EPS = 1e-5f;
constexpr int NCH = 64, CL = 14;           // chunked scan: 64*14 = 896 >= 866
static_assert(NCH * CL >= NTOK, "chunks must cover sequence");

// async global -> LDS, 16B per lane (wave-uniform LDS base + lane*16)
__device__ __forceinline__ void gload16(const void* g, void* l) {
    __builtin_amdgcn_global_load_lds((const __attribute__((address_space(1))) void*)g,
                                     (__attribute__((address_space(3))) void*)l, 16, 0, 0);
}

// ---------------------------------------------------------------- f32 -> bf16
__global__ void cvt_kernel(const float* __restrict__ src, bf* __restrict__ dst, int n4) {
    int i = blockIdx.x * 256 + threadIdx.x;
    if (i >= n4) return;
    f32x4 v = ((const f32x4*)src)[i];
    bf o[4];
    o[0] = (bf)v[0]; o[1] = (bf)v[1]; o[2] = (bf)v[2]; o[3] = (bf)v[3];
    *(uint2*)&dst[i * 4] = *(uint2*)o;
}

// ---------------- build combined dt/bc weight: [ld][544][512] bf16
// rows 0..511: Fold = Wdt(512x32)·Wx[0:32]  ;  rows 512..543: Wx[32:64] (B,C)
__global__ void fold_kernel(const float* __restrict__ Wdt, const float* __restrict__ Wx,
                            bf* __restrict__ out) {
    int idx = blockIdx.x * 256 + threadIdx.x;     // NL*2*544*512 total
    int k = idx & 511; int rest = idx >> 9;
    int row = rest % 544; int ld = rest / 544;
    float s;
    if (row < 512) {
        const float* wd = Wdt + ((size_t)ld * 512 + row) * 32;
        const float* wx = Wx + (size_t)ld * 64 * 512 + k;
        s = 0.f;
#pragma unroll 8
        for (int r = 0; r < 32; r++) s += wd[r] * wx[(size_t)r * 512];
    } else {
        s = Wx[(size_t)ld * 64 * 512 + (size_t)(32 + row - 512) * 512 + k];
    }
    out[((size_t)ld * 544 + row) * 512 + k] = (bf)s;
}

// ---------------- per-channel A20 / fast-flag precompute (once per forward)
__global__ void a20_kernel(const float* __restrict__ Alog, float* __restrict__ a20,
                           float* __restrict__ lcf, int total) {
    int i = blockIdx.x * 256 + threadIdx.x;    // NL*2*512
    if (i >= total) return;
    constexpr float L2E = 1.4426950408889634f;
    const float* ap = Alog + (size_t)i * DS;
    float a0 = -__expf(ap[0]) * L2E;
    bool lc = true;
#pragma unroll
    for (int s = 1; s < 16; s++) {
        float as = -__expf(ap[s]) * L2E;
        lc = lc && (fabsf(as - (s + 1) * a0) <= 1e-4f * fabsf(as));
    }
    a20[i] = a0;
    lcf[i] = lc ? 1.f : 0.f;
}

// ---------------------------------------------------------------- mean / std
__global__ __launch_bounds__(256) void meanstd_kernel(const float* __restrict__ xe,
                               float* __restrict__ mean, float* __restrict__ stdv) {
    __shared__ float sm[2][4][64];
    int b = blockIdx.y;
    int vl = threadIdx.x & 63;
    int tg = threadIdx.x >> 6;
    int v = blockIdx.x * 64 + vl;
    float s = 0.f, sq = 0.f;
    if (v < NVAR) {
        const float* p = xe + (size_t)b * SEQ * NVAR + (size_t)tg * 128 * NVAR + v;
#pragma unroll 4
        for (int t = 0; t < 128; t++) {
            float x = p[(size_t)t * NVAR];
            s += x; sq += x * x;
        }
    }
    sm[0][tg][vl] = s; sm[1][tg][vl] = sq;
    __syncthreads();
    if (tg == 0 && v < NVAR) {
        s  = sm[0][0][vl] + sm[0][1][vl] + sm[0][2][vl] + sm[0][3][vl];
        sq = sm[1][0][vl] + sm[1][1][vl] + sm[1][2][vl] + sm[1][3][vl];
        float mu = s * (1.f / SEQ);
        float var = sq * (1.f / SEQ) - mu * mu;
        mean[b * NVAR + v] = mu;
        stdv[b * NVAR + v] = sqrtf(var + EPS);
    }
}

// ------------------------------------------------- tok build (transpose+norm)
__global__ void tok_kernel(const float* __restrict__ xe, const float* __restrict__ xm,
                           const float* __restrict__ mean, const float* __restrict__ stdv,
                           bf* __restrict__ tok) {
    __shared__ float tile[32][33];
    int b = blockIdx.z;
    int v0 = blockIdx.x * 32, s0 = blockIdx.y * 32;
    int tx = threadIdx.x, ty = threadIdx.y;  // 32 x 8
    int v = v0 + tx;
    float mu = 0.f, rs = 0.f;
    if (v < NVAR) { mu = mean[b * NVAR + v]; rs = 1.f / stdv[b * NVAR + v]; }
#pragma unroll
    for (int j = 0; j < 4; j++) {
        int s = s0 + ty + j * 8;
        float val = 0.f;
        if (v < NVAR)       val = (xe[((size_t)b * SEQ + s) * NVAR + v] - mu) * rs;
        else if (v < NTOK)  val = xm[((size_t)b * SEQ + s) * NMARK + (v - NVAR)];
        tile[ty + j * 8][tx] = val;
    }
    __syncthreads();
#pragma unroll
    for (int j = 0; j < 4; j++) {
        int n = v0 + ty + j * 8;
        if (n < NTOK)
            tok[((size_t)b * NTOK + n) * SEQ + s0 + tx] = (bf)tile[tx][ty + j * 8];
    }
}

// ---------------------------------------------------------------- GEMM
// C[M,N] = A[M,K](bf16) * W[N,K]^T (bf16), f32 accumulate.
// 64x128 tile, 8 waves / 512 threads; each wave owns 32x32 output.
// LDS = 48 KB double-buffered -> 3 blocks/CU. Counted-vmcnt pipeline.
// DTBC: dt output stored as fp16 (CT=_Float16), B/C as f32 to C2.
template <int BN, int ACT, bool BIAS, bool RES, bool HEAD, bool DTBC, typename CT>
__global__ __launch_bounds__(512, 6) void gemm_kernel(
    const bf* __restrict__ A0, const bf* __restrict__ A1,
    const bf* __restrict__ W0, const bf* __restrict__ W1,
    CT* __restrict__ C, float* __restrict__ C2,
    const float* __restrict__ bias, const bf* __restrict__ res,
    int Mreal, int Nreal, int K, int lda, int ldw, int ksplit, int ldc,
    size_t sAz, size_t sWz, size_t sCz, size_t sC2z, size_t sBiasz,
    const float* __restrict__ mean, const float* __restrict__ stdv) {
    constexpr int BM = 64, BK = 64;
    static_assert(BN == 128, "8-wave layout assumes 64x128 tile");
    __shared__ __align__(16) bf Als[2][BM * BK];
    __shared__ __align__(16) bf Bls[2][BN * BK];

    // ---- XCD-chunked bijective remap (m204 formula), n fastest within m ----
    int gx = gridDim.x, gy = gridDim.y;
    int gxy = gx * gy;
    int nbt = gxy * gridDim.z;
    int id = blockIdx.x + gx * (blockIdx.y + gy * blockIdx.z);
    int q8 = nbt >> 3, r8 = nbt & 7;
    int xcd = id & 7, rank = id >> 3;
    int w = xcd * q8 + (xcd < r8 ? xcd : r8) + rank;
    int z = w / gxy;
    int rem = w - z * gxy;
    int m0 = (rem / gy) * BM;
    int n0 = (rem % gy) * BN;

    A0 += (size_t)z * sAz; W0 += (size_t)z * sWz; C += (size_t)z * sCz;
    if (DTBC) C2 += (size_t)z * sC2z;
    if (BIAS) bias += (size_t)z * sBiasz;
    int tid = threadIdx.x, lane = tid & 63, wave = tid >> 6;   // 0..7
    int wm = wave >> 2, wn = wave & 3;        // 2 row-halves x 4 col-quarters
    int q = lane >> 4, ml = lane & 15;
    int srow = lane >> 3;
    int aswz = ((lane & 7) ^ srow) * 8;          // global col offset (elems)
    int swz = ((q ^ (ml & 7))) * 8;

    f32x4 acc[2][2];
#pragma unroll
    for (int i = 0; i < 2; i++)
#pragma unroll
        for (int j = 0; j < 2; j++) { acc[i][j][0] = 0.f; acc[i][j][1] = 0.f; acc[i][j][2] = 0.f; acc[i][j][3] = 0.f; }

    // per-wave: 3 async loads per stage (1 A row-group + 2 B row-groups)
    auto stage = [&](int kt, int buf) {
        const bf* ab = (ksplit && kt >= ksplit) ? (A1 + (kt - ksplit)) : (A0 + kt);
        const bf* wb = (ksplit && kt >= ksplit) ? (W1 + (kt - ksplit)) : (W0 + kt);
        {
            int r = wave * 8;                  // 8 waves x 8 rows = 64 A rows
            gload16(ab + (size_t)(m0 + r + srow) * lda + aswz, &Als[buf][r * BK]);
        }
#pragma unroll
        for (int i = 0; i < 2; i++) {
            int r = wave * 16 + i * 8;         // 8 waves x 16 rows = 128 B rows
            gload16(wb + (size_t)(n0 + r + srow) * ldw + aswz, &Bls[buf][r * BK]);
        }
    };

    stage(0, 0);
    int cur = 0;
    for (int kt = 0; kt < K; kt += BK) {
        bool pf = (kt + BK < K);
        if (pf) stage(kt + BK, cur ^ 1);       // prefetch next tile (3 loads)
        if (pf) asm volatile("s_waitcnt vmcnt(3)" ::: "memory");
        else    asm volatile("s_waitcnt vmcnt(0)" ::: "memory");
        __builtin_amdgcn_s_barrier();           // all waves' tile-t data in LDS
        __builtin_amdgcn_sched_barrier(0);      // pin LDS reads after barrier
#pragma unroll
        for (int kk = 0; kk < BK; kk += 32) {
            bfrag af[2], bff[2];
#pragma unroll
            for (int i = 0; i < 2; i++)
                af[i] = *(bfrag*)&Als[cur][(wm * 32 + i * 16 + ml) * BK + (swz ^ kk)];
#pragma unroll
            for (int j = 0; j < 2; j++)
                bff[j] = *(bfrag*)&Bls[cur][(wn * 32 + j * 16 + ml) * BK + (swz ^ kk)];
#pragma unroll
            for (int i = 0; i < 2; i++)
#pragma unroll
                for (int j = 0; j < 2; j++)
                    acc[i][j] = __builtin_amdgcn_mfma_f32_16x16x32_bf16(bff[j], af[i], acc[i][j], 0, 0, 0);
        }
        __builtin_amdgcn_sched_barrier(0);      // pin LDS reads before barrier
        __builtin_amdgcn_s_barrier();           // all waves done reading cur
        cur ^= 1;
    }

    // epilogue: acc[i][j][r] -> row = m0+wm*32+i*16+ml ; col = n0+wn*32+j*16+q*4+r
#pragma unroll
    for (int i = 0; i < 2; i++) {
        int row = m0 + wm * 32 + i * 16 + ml;
        if (row >= Mreal) continue;
#pragma unroll
        for (int j = 0; j < 2; j++) {
            int colb = n0 + wn * 32 + j * 16 + q * 4;
            if (colb >= Nreal) continue;          // N multiples of 4 -> whole quad in/out
            f32x4 x = acc[i][j];
            if constexpr (BIAS) {
                if (!DTBC || colb < 512) {
                    f32x4 bv = *(const f32x4*)&bias[colb];
#pragma unroll
                    for (int r = 0; r < 4; r++) x[r] += bv[r];
                }
            }
            if constexpr (DTBC) {
                if (colb < 512) {
                    h4 hv;
#pragma unroll
                    for (int r = 0; r < 4; r++) {
                        float xs = (x[r] > 20.f) ? x[r] : __logf(1.f + __expf(x[r]));  // softplus
                        hv[r] = (_Float16)xs;
                    }
                    *(h4*)&C[(size_t)row * 512 + colb] = hv;        // CT=_Float16
                } else {
                    *(f32x4*)&C2[(size_t)row * 32 + (colb - 512)] = x;
                }
            } else {
                if constexpr (ACT == 1) {
#pragma unroll
                    for (int r = 0; r < 4; r++)
                        x[r] = 0.5f * x[r] * (1.f + erff(x[r] * 0.70710678118654752f));
                }
                if constexpr (RES) {
                    bf4 rv = *(const bf4*)&res[(size_t)row * DM + colb];
#pragma unroll
                    for (int r = 0; r < 4; r++) x[r] += (float)rv[r];
                }
                if constexpr (HEAD) {
                    int bidx = row / NTOK, n = row - bidx * NTOK;
                    if (n < NVAR) {
                        float sc = stdv[bidx * NVAR + n], mm = mean[bidx * NVAR + n];
#pragma unroll
                        for (int r = 0; r < 4; r++) {
                            int col = colb + r;
                            if (col < Nreal)
                                C[((size_t)bidx * PRED + col) * NVAR + n] = (CT)(x[r] * sc + mm);
                        }
                    }
                } else {
                    bf4 ov;
#pragma unroll
                    for (int r = 0; r < 4; r++) ov[r] = (bf)x[r];
                    *(bf4*)&C[(size_t)row * ldc + colb] = ov;
                }
            }
        }
    }
    if (HEAD && blockIdx.x == 0 && blockIdx.y == 0 && blockIdx.z == 0 && tid == 0)
        C[(size_t)BSZ * PRED * NVAR] = (CT)0.f;  // loss_reg = 0
}

// ---------------------------------------------------------------- conv + silu
__global__ void conv_kernel(const bf* __restrict__ xz, const float* __restrict__ cw,
                            const float* __restrict__ cb, bf* __restrict__ xc, int Mc) {
    int id = blockIdx.x * 256 + threadIdx.x;   // 2*Mc*64 total
    int dir = id / (Mc * 64); int rem = id - dir * (Mc * 64);
    int token = rem >> 6; int ch0 = (rem & 63) * 8;
    int t = token % NTOK;
    const bf* xb = xz + (size_t)token * (4 * DM) + dir * (2 * DM) + ch0;
    bfrag xt = *(const bfrag*)xb;
    bfrag xn;
#pragma unroll
    for (int i = 0; i < 8; i++) xn[i] = (bf)0.f;
    int tn = dir ? t + 1 : t - 1;
    if ((unsigned)tn < (unsigned)NTOK)
        xn = *(const bfrag*)(xb + (dir ? (4 * DM) : -(4 * DM)));
    const float2* cwp = (const float2*)cw + ((size_t)dir * DM + ch0);
    const float*  cbp = cb + (size_t)dir * DM + ch0;
    bfrag ov;
#pragma unroll
    for (int jj = 0; jj < 8; jj++) {
        float2 w = cwp[jj];
        float x = (float)xn[jj] * w.x + (float)xt[jj] * w.y + cbp[jj];
        x = x / (1.f + __expf(-x));
        ov[jj] = (bf)x;
    }
    *(bfrag*)(xc + (size_t)dir * Mc * DM + (size_t)token * DM + ch0) = ov;
}

// ---------------------------------------------------------------- chunked scan
// Packed: each lane owns 4 consecutive channels. NCH=64 (CL=14), CB=16 ->
// 2048 blocks x 2 waves = 4096 waves (4/SIMD residency, R9/R10 lesson).
// scanC (FINAL) writes y IN PLACE into xc's storage ([dir][tok][512]) --
// each element's read (prefetched at t-1) precedes its write; single owner
// per (dir,t,d). xc/y therefore must NOT be __restrict__.
// hloc chunk state is fp16 (halves scratch -> doubles CB).
template <bool FINAL>
__global__ __launch_bounds__(128, 2) void scan_chunk_kernel(
    const fp16* __restrict__ dtc, const float* __restrict__ dbc,
    const bf* xc, const bf* __restrict__ xz,
    const float* __restrict__ Alog, const float* __restrict__ A20g,
    const float* __restrict__ LCg, const float* __restrict__ Dp,
    fp16* __restrict__ hloc, float* __restrict__ dtsums,
    bf* y, int Mc) {
    __shared__ __align__(16) float row[2][32];
    int wid = threadIdx.x >> 6;                // cg: channel group 0/1
    int lane = threadIdx.x & 63;
    int b = blockIdx.x;
    int zc = blockIdx.y; int dir = zc / NCH, c = zc - dir * NCH;
    int d0 = wid * 256 + lane * 4;             // 4 consecutive channels
    int dd0 = dir * DM + d0;

    constexpr float L2E = 1.4426950408889634f;
    f32x4 a20v = *(const f32x4*)&A20g[dd0];
    f32x4 lcv  = *(const f32x4*)&LCg[dd0];
    float A20[4];
#pragma unroll
    for (int cc = 0; cc < 4; cc++) A20[cc] = a20v[cc];
    bool lc = (lcv[0] + lcv[1] + lcv[2] + lcv[3]) == 4.f;
    bool fast = (__ballot(lc) == ~0ull);
    float Dd[4];
#pragma unroll
    for (int cc = 0; cc < 4; cc++) Dd[cc] = FINAL ? Dp[dd0 + cc] : 0.f;

    const size_t hbase = ((size_t)(b * 2 + dir) * NCH + c) * 8192;   // 16*512
    float h[4][16];
    if (FINAL) {
#pragma unroll
        for (int s = 0; s < 16; s++) {
            h4 hv = *(const h4*)&hloc[hbase + (size_t)s * 512 + d0];
#pragma unroll
            for (int cc = 0; cc < 4; cc++) h[cc][s] = (float)hv[cc];
        }
    } else {
#pragma unroll
        for (int cc = 0; cc < 4; cc++)
#pragma unroll
            for (int s = 0; s < 16; s++) h[cc][s] = 0.f;
    }
    float dtsum[4] = {0.f, 0.f, 0.f, 0.f};

    const int t0 = c * CL;
    const int t1e = (t0 + CL < NTOK) ? t0 + CL : NTOK;
    const long step = dir ? -1 : 1;

    const fp16* dtp = nullptr; const float* bcp = nullptr;
    const bf* xcp = nullptr; const bf* xzp = nullptr; bf* yp = nullptr;
    h4 dtq = {(_Float16)0.f, (_Float16)0.f, (_Float16)0.f, (_Float16)0.f};
    bf4 xq; bf4 zq;
#pragma unroll
    for (int cc = 0; cc < 4; cc++) { xq[cc] = (bf)0.f; zq[cc] = (bf)0.f; }
    f32x4 gq = {0.f, 0.f, 0.f, 0.f};
    if (t0 < t1e) {
        long tok0 = (long)b * NTOK + (dir ? (NTOK - 1 - t0) : t0);
        dtp = dtc + (size_t)dir * Mc * 512 + (size_t)tok0 * 512 + d0;
        bcp = dbc + ((size_t)dir * Mc + (size_t)tok0) * 32;
        xcp = xc + (size_t)dir * Mc * 512 + (size_t)tok0 * 512 + d0;
        dtq = *(const h4*)dtp;
        if (lane < 8) gq = ((const f32x4*)bcp)[lane];
        xq = *(const bf4*)xcp;
        if (FINAL) {
            xzp = xz + (size_t)tok0 * 2048 + dir * 1024 + 512 + d0;
            yp  = y + (size_t)dir * Mc * 512 + (size_t)tok0 * 512 + d0;  // in-place over xc
            zq = *(const bf4*)xzp;
        }
    }
    const long sdt = step * 512, sbc = step * 32, sxc = step * 512;
    const long sxz = step * 2048, sy = step * 512;

    for (int t = t0; t < t1e; t++) {
        if (lane < 8) ((f32x4*)row[wid])[lane] = gq;
        float dtv[4], xv[4], zv[4], dtx[4];
#pragma unroll
        for (int cc = 0; cc < 4; cc++) {
            dtv[cc] = (float)dtq[cc];
            xv[cc] = (float)xq[cc];
            if (FINAL) zv[cc] = (float)zq[cc];
            dtx[cc] = dtv[cc] * xv[cc];
            dtsum[cc] += dtv[cc];
        }
        bf* ypc = yp;
        if (t + 1 < t1e) {                     // prefetch next token (reads precede y[t] write)
            dtp += sdt; bcp += sbc; xcp += sxc;
            dtq = *(const h4*)dtp;
            if (lane < 8) gq = ((const f32x4*)bcp)[lane];
            xq = *(const bf4*)xcp;
            if (FINAL) { xzp += sxz; zq = *(const bf4*)xzp; yp += sy; }
        }
        const f32x4* rv = (const f32x4*)row[wid];
        float yva[4] = {0.f, 0.f, 0.f, 0.f};
        if (fast) {
            float r[4], r2[4], r3[4], r4[4], bse[4];
#pragma unroll
            for (int cc = 0; cc < 4; cc++) {
                r[cc] = exp2f(dtv[cc] * A20[cc]);
                r2[cc] = r[cc] * r[cc]; r3[cc] = r2[cc] * r[cc]; r4[cc] = r2[cc] * r2[cc];
                bse[cc] = r[cc];
            }
#pragma unroll
            for (int i = 0; i < 4; i++) {
                f32x4 Bv = rv[i];
                f32x4 Cv = rv[4 + i];
#pragma unroll
                for (int cc = 0; cc < 4; cc++) {
                    int s = i * 4;
                    float p0 = bse[cc], p1 = p0 * r[cc], p2 = p0 * r2[cc], p3 = p0 * r3[cc];
                    h[cc][s + 0] = p0 * h[cc][s + 0] + dtx[cc] * Bv[0];
                    h[cc][s + 1] = p1 * h[cc][s + 1] + dtx[cc] * Bv[1];
                    h[cc][s + 2] = p2 * h[cc][s + 2] + dtx[cc] * Bv[2];
                    h[cc][s + 3] = p3 * h[cc][s + 3] + dtx[cc] * Bv[3];
                    if (FINAL)
                        yva[cc] += Cv[0] * h[cc][s + 0] + Cv[1] * h[cc][s + 1]
                                 + Cv[2] * h[cc][s + 2] + Cv[3] * h[cc][s + 3];
                    bse[cc] *= r4[cc];
                }
            }
        } else {
            // slow path (never taken for this model's Alog; kept for correctness)
#pragma unroll
            for (int i = 0; i < 4; i++) {
                f32x4 Bv = rv[i];
                f32x4 Cv = rv[4 + i];
#pragma unroll
                for (int cc = 0; cc < 4; cc++) {
#pragma unroll
                    for (int jj = 0; jj < 4; jj++) {
                        int s = i * 4 + jj;
                        float A2 = -__expf(Alog[(size_t)(dd0 + cc) * DS + s]) * L2E;
                        float a = exp2f(dtv[cc] * A2);
                        h[cc][s] = a * h[cc][s] + dtx[cc] * Bv[jj];
                        if (FINAL) yva[cc] += Cv[jj] * h[cc][s];
                    }
                }
            }
        }
        if (FINAL) {
            bf4 ov;
#pragma unroll
            for (int cc = 0; cc < 4; cc++) {
                float sz = zv[cc] / (1.f + __expf(-zv[cc]));
                ov[cc] = (bf)((yva[cc] + Dd[cc] * xv[cc]) * sz);
            }
            *(bf4*)ypc = ov;
        }
    }
    if (!FINAL) {
#pragma unroll
        for (int s = 0; s < 16; s++) {
            h4 hv;
#pragma unroll
            for (int cc = 0; cc < 4; cc++) hv[cc] = (_Float16)h[cc][s];
            *(h4*)&hloc[hbase + (size_t)s * 512 + d0] = hv;
        }
        f32x4 dv;
#pragma unroll
        for (int cc = 0; cc < 4; cc++) dv[cc] = dtsum[cc];
        *(f32x4*)&dtsums[((size_t)(b * 2 + dir) * NCH + c) * 512 + d0] = dv;
    }
}

// Phase B: combine chunk summaries (serial over NCH chunks per group).
// hloc (fp16) layout [g][c][s][d]; dtsums (f32) [g][c][d]. One thread per
// (g,s,d): coalesced on d. aprod = exp2(dtsum * A2[s]) on the fly.
__global__ void scan_fix_kernel(fp16* __restrict__ hloc, const float* __restrict__ dtsums,
                                const float* __restrict__ Alog, int total) {
    int tid = blockIdx.x * 256 + threadIdx.x;
    if (tid >= total) return;
    int d = tid & 511;
    int s = (tid >> 9) & 15;
    int g = tid >> 13;                 // b*2+dir
    int dir = g & 1;
    float A2s = -__expf(Alog[((size_t)(dir * DM + d)) * DS + s]) * 1.4426950408889634f;
    size_t i0 = (size_t)g * NCH * 8192 + (size_t)s * 512 + d;
    size_t d0 = (size_t)g * NCH * 512 + d;
    float H = 0.f;
#pragma unroll 8
    for (int c = 0; c < NCH; c++) {
        size_t ix = i0 + (size_t)c * 8192;
        float hl = (float)hloc[ix];
        float ap = exp2f(dtsums[d0 + (size_t)c * 512] * A2s);
        hloc[ix] = (_Float16)H;
        H = hl + ap * H;
    }
}

// ---------------------------------------------------------------- LayerNorm
__global__ __launch_bounds__(256) void ln_kernel(const bf* X, bf* Y,
                                                 const float* __restrict__ g, const float* __restrict__ bb) {
    int token = blockIdx.x * 4 + (threadIdx.x >> 6);
    int lane = threadIdx.x & 63;
    bfrag xv = *(const bfrag*)(X + (size_t)token * DM + lane * 8);
    float xf[8]; float s = 0.f, sq = 0.f;
#pragma unroll
    for (int j = 0; j < 8; j++) { xf[j] = (float)xv[j]; s += xf[j]; sq += xf[j] * xf[j]; }
#pragma unroll
    for (int o = 1; o < 64; o <<= 1) { s += __shfl_xor(s, o); sq += __shfl_xor(sq, o); }
    float mu = s * (1.f / DM);
    float rs = rsqrtf(sq * (1.f / DM) - mu * mu + EPS);
    f32x4 g0 = ((const f32x4*)g)[lane * 2], g1 = ((const f32x4*)g)[lane * 2 + 1];
    f32x4 b0 = ((const f32x4*)bb)[lane * 2], b1 = ((const f32x4*)bb)[lane * 2 + 1];
    bfrag ov;
#pragma unroll
    for (int j = 0; j < 8; j++) {
        float gg = (j < 4) ? g0[j] : g1[j - 4];
        float bbv = (j < 4) ? b0[j] : b1[j - 4];
        ov[j] = (bf)((xf[j] - mu) * rs * gg + bbv);
    }
    *(bfrag*)(Y + (size_t)token * DM + lane * 8) = ov;
}

// ---------------------------------------------------------------- launch
extern "C" void kernel_launch(void* const* d_in, const int* in_sizes, int n_in,
                              void* d_out, int out_size, void* d_ws, size_t ws_size,
                              hipStream_t stream) {
    const float* x_enc = (const float*)d_in[0];
    const float* x_mark = (const float*)d_in[1];
    const float* W_emb = (const float*)d_in[4];
    const float* b_emb = (const float*)d_in[5];
    const float* mWin = (const float*)d_in[6];
    const float* mcw = (const float*)d_in[7];
    const float* mcb = (const float*)d_in[8];
    const float* mWx = (const float*)d_in[9];
    const float* mWdt = (const float*)d_in[10];
    const float* mbdt = (const float*)d_in[11];
    const float* mAlog = (const float*)d_in[12];
    const float* mD = (const float*)d_in[13];
    const float* mWout = (const float*)d_in[14];
    const float* W1w = (const float*)d_in[15];
    const float* b1w = (const float*)d_in[16];
    const float* W2w = (const float*)d_in[17];
    const float* b2w = (const float*)d_in[18];
    const float* ln1g = (const float*)d_in[19];
    const float* ln1b = (const float*)d_in[20];
    const float* ln2g = (const float*)d_in[21];
    const float* ln2b = (const float*)d_in[22];
    const float* lnfg = (const float*)d_in[23];
    const float* lnfb = (const float*)d_in[24];
    const float* headW = (const float*)d_in[25];
    const float* headb = (const float*)d_in[26];

    auto a256 = [](size_t x) { return (x + 255) & ~(size_t)255; };
    char* ws = (char*)d_ws;
    size_t off = 0;
    auto alloc = [&](size_t n) { size_t r = off; off += a256(n); return ws + r; };
    float* mean = (float*)alloc((size_t)BSZ * NVAR * 4);
    float* stdv = (float*)alloc((size_t)BSZ * NVAR * 4);
    bf* h  = (bf*)alloc((size_t)M * DM * 2);
    bf* t1 = (bf*)alloc((size_t)M * DM * 2);   // tok / hsum / ff
    bf* t2 = (bf*)alloc((size_t)M * DM * 2);   // h2
    // bf16-converted GEMM weights
    constexpr int nEmb = 512 * 512, nWin = NL * 2 * 1024 * 512,
                  nWout = NL * 2 * 512 * 512, nW1 = NL * DFF * DM, nW2 = NL * DM * DFF,
                  nHead = PRED * DM, nComb = NL * 2 * 544 * 512;
    bf* wEmb  = (bf*)alloc((size_t)nEmb * 2);
    bf* wWin  = (bf*)alloc((size_t)nWin * 2);
    bf* wWout = (bf*)alloc((size_t)nWout * 2);
    bf* wW1   = (bf*)alloc((size_t)nW1 * 2);
    bf* wW2   = (bf*)alloc((size_t)nW2 * 2);
    bf* wHead = (bf*)alloc((size_t)nHead * 2);
    bf* wComb = (bf*)alloc((size_t)nComb * 2);
    float* aA20 = (float*)alloc((size_t)NL * 2 * 512 * 4);   // precomputed A20
    float* aLC  = (float*)alloc((size_t)NL * 2 * 512 * 4);   // fast flags
    size_t fixedEnd = off;

    // adaptive chunk size: CB batches per chunk (no ycc -- y written in-place
    // into xcc; hloc fp16 -> chunk footprint ~9.7 MB per CB unit)
    auto scanScr = [&](size_t cb) { return cb * 2 * (size_t)NCH * 8192 * 2; };  // hloc fp16
    auto dtsScr  = [&](size_t cb) { return cb * 2 * (size_t)NCH * 512 * 4; };   // dtsums f32
    int CB = 1;
    {
        int cbs[6] = {32, 16, 8, 4, 2, 1};
        for (int i = 0; i < 6; i++) {
            size_t mc = (size_t)cbs[i] * NTOK;
            size_t chunkB = a256(mc * 4096) + a256(mc * 2048) + a256(mc * 256)
                          + a256(mc * 2048)
                          + a256(scanScr(cbs[i])) + a256(dtsScr(cbs[i]));
            if (fixedEnd + chunkB <= ws_size) { CB = cbs[i]; break; }
        }
    }
    const size_t Mc = (size_t)CB * NTOK;
    size_t co = fixedEnd;
    bf* xzc = (bf*)(ws + co);        co += a256(Mc * 4096);
    bf* xcc = (bf*)(ws + co);        co += a256(Mc * 2048);   // conv out; scanC y in-place
    float* dbcc = (float*)(ws + co); co += a256(Mc * 256);
    fp16* dtcc = (fp16*)(ws + co);   co += a256(Mc * 2048);   // fp16, 2 dirs x 512
    fp16* hloc = (fp16*)(ws + co);   co += a256(scanScr(CB));
    float* dtsums = (float*)(ws + co);
    const int NC = BSZ / CB;
    const int MTc = (int)((Mc + 63) / 64);     // BM=64 m-panels
    constexpr int MT = (M + 63) / 64;          // 433 (exact: 27712 = 433*64)
    const int fixTotal = CB * 2 * 16 * 512;

    // weight conversion f32 -> bf16, combined dt/bc weight, A20 precompute
    cvt_kernel<<<(nEmb / 4 + 255) / 256, 256, 0, stream>>>(W_emb, wEmb, nEmb / 4);
    cvt_kernel<<<(nWin / 4 + 255) / 256, 256, 0, stream>>>(mWin, wWin, nWin / 4);
    cvt_kernel<<<(nWout / 4 + 255) / 256, 256, 0, stream>>>(mWout, wWout, nWout / 4);
    cvt_kernel<<<(nW1 / 4 + 255) / 256, 256, 0, stream>>>(W1w, wW1, nW1 / 4);
    cvt_kernel<<<(nW2 / 4 + 255) / 256, 256, 0, stream>>>(W2w, wW2, nW2 / 4);
    cvt_kernel<<<(nHead / 4 + 255) / 256, 256, 0, stream>>>(headW, wHead, nHead / 4);
    fold_kernel<<<(nComb + 255) / 256, 256, 0, stream>>>(mWdt, mWx, wComb);
    a20_kernel<<<(NL * 2 * 512 + 255) / 256, 256, 0, stream>>>(mAlog, aA20, aLC, NL * 2 * 512);

    meanstd_kernel<<<dim3(14, BSZ), 256, 0, stream>>>(x_enc, mean, stdv);
    tok_kernel<<<dim3(28, 16, BSZ), dim3(32, 8), 0, stream>>>(x_enc, x_mark, mean, stdv, t1);
    // embedding: h = tok · W_emb^T + b_emb
    gemm_kernel<128, 0, true, false, false, false, bf><<<dim3(MT, 4), 512, 0, stream>>>(
        t1, nullptr, wEmb, nullptr, h, nullptr, b_emb, nullptr,
        M, DM, SEQ, SEQ, SEQ, 0, DM, 0, 0, 0, 0, 0, nullptr, nullptr);

    for (int l = 0; l < NL; l++) {
        const bf* Winl = wWin + (size_t)l * 2 * 1024 * 512;
        const float* cwl = mcw + (size_t)l * 2 * DM * 2;
        const float* cbl = mcb + (size_t)l * 2 * DM;
        const bf* Combl = wComb + (size_t)l * 2 * 544 * 512;
        const float* bdtl = mbdt + (size_t)l * 2 * DM;
        const float* Alogl = mAlog + (size_t)l * 2 * 512 * 16;
        const float* A20l = aA20 + (size_t)l * 2 * 512;
        const float* LCl  = aLC  + (size_t)l * 2 * 512;
        const float* Dl = mD + (size_t)l * 2 * DM;
        const bf* Woutl = wWout + (size_t)l * 2 * 512 * 512;
        const bf* W1l = wW1 + (size_t)l * DFF * DM;
        const bf* W2l = wW2 + (size_t)l * DM * DFF;

        for (int c = 0; c < NC; c++) {
            size_t coff = (size_t)c * Mc;  // token offset
            // xz = h · [Win_f ; Win_r]^T   (N = 2048)
            gemm_kernel<128, 0, false, false, false, false, bf><<<dim3(MTc, 16), 512, 0, stream>>>(
                h + coff * DM, nullptr, Winl, nullptr, xzc, nullptr, nullptr, nullptr,
                (int)Mc, 2048, 512, 512, 512, 0, 2048, 0, 0, 0, 0, 0, nullptr, nullptr);
            // conv + silu (both directions)
            conv_kernel<<<(int)(2 * Mc * 64 / 256), 256, 0, stream>>>(xzc, cwl, cbl, xcc, (int)Mc);
            // fused dt (softplus -> fp16, N=0..511) + B,C (N=512..543, f32) GEMM
            gemm_kernel<128, 0, true, false, false, true, _Float16><<<dim3(MTc, 5, 2), 512, 0, stream>>>(
                xcc, nullptr, Combl, nullptr, dtcc, dbcc, bdtl, nullptr,
                (int)Mc, 544, 512, 512, 512, 0, 512,
                Mc * 512, (size_t)544 * 512, Mc * 512, Mc * 32, 512, nullptr, nullptr);
            // chunked scan: A (local) -> B (fix) -> C (final, y in-place into xcc)
            scan_chunk_kernel<false><<<dim3(CB, 2 * NCH), 128, 0, stream>>>(
                dtcc, dbcc, xcc, xzc, Alogl, A20l, LCl, Dl, hloc, dtsums, xcc, (int)Mc);
            scan_fix_kernel<<<(fixTotal + 255) / 256, 256, 0, stream>>>(hloc, dtsums, Alogl, fixTotal);
            scan_chunk_kernel<true><<<dim3(CB, 2 * NCH), 128, 0, stream>>>(
                dtcc, dbcc, xcc, xzc, Alogl, A20l, LCl, Dl, hloc, dtsums, xcc, (int)Mc);
            // hsum = h + y_f·Wout_f^T + y_r·Wout_r^T  (y in xcc layout, lda=512)
            gemm_kernel<128, 0, false, true, false, false, bf><<<dim3(MTc, 4), 512, 0, stream>>>(
                xcc, xcc + Mc * 512, Woutl, Woutl + 512 * 512, t1 + coff * DM, nullptr, nullptr, h + coff * DM,
                (int)Mc, DM, 1024, 512, 512, 512, DM, 0, 0, 0, 0, 0, nullptr, nullptr);
        }
        ln_kernel<<<M / 4, 256, 0, stream>>>(t1, t2, ln1g + l * DM, ln1b + l * DM);
        // FFN
        gemm_kernel<128, 1, true, false, false, false, bf><<<dim3(MT, 4), 512, 0, stream>>>(
            t2, nullptr, W1l, nullptr, t1, nullptr, b1w + l * DFF, nullptr,
            M, DFF, DM, DM, DM, 0, DFF, 0, 0, 0, 0, 0, nullptr, nullptr);
        gemm_kernel<128, 0, true, true, false, false, bf><<<dim3(MT, 4), 512, 0, stream>>>(
            t1, nullptr, W2l, nullptr, h, nullptr, b2w + l * DM, t2,
            M, DM, DFF, DFF, DFF, 0, DM, 0, 0, 0, 0, 0, nullptr, nullptr);
        ln_kernel<<<M / 4, 256, 0, stream>>>(h, h, ln2g + l * DM, ln2b + l * DM);
    }

    ln_kernel<<<M / 4, 256, 0, stream>>>(h, t1, lnfg, lnfb);
    // head + de-normalize + scatter to (B, PRED, NVAR), plus loss scalar
    gemm_kernel<128, 0, true, false, true, false, float><<<dim3(MT, 1), 512, 0, stream>>>(
        t1, nullptr, wHead, nullptr, (float*)d_out, nullptr, headb, nullptr,
        M, PRED, DM, DM, DM, 0, 1, 0, 0, 0, 0, 0, mean, stdv);
}